// Round 2
// baseline (14068.437 us; speedup 1.0000x reference)
//
#include <hip/hip_runtime.h>
#include <hip/hip_bf16.h>

#define DEV __device__ __forceinline__

constexpr int kB = 16, kC = 32, kT = 512, kS = 128, kBC = 512, kLatent = 128;
constexpr float kEps = 1e-8f;

DEV float ldf(const float* p, size_t i) { return p[i]; }
DEV float ldf(const __hip_bfloat16* p, size_t i) { return __bfloat162float(p[i]); }
DEV void stf(float* p, size_t i, float v) { p[i] = v; }
DEV void stf(__hip_bfloat16* p, size_t i, float v) { p[i] = __float2bfloat16(v); }

// ---- Kernel 1: per-(b,c) downsample + min/max normalize + sqrt term ----
__global__ void gaf_stats_kernel(const float* __restrict__ x_raw,
                                 float* __restrict__ xn, float* __restrict__ sq) {
    int bc = blockIdx.x;       // 512
    int s  = threadIdx.x;      // 128
    const float* xp = x_raw + (size_t)bc * kT;
    float v = 0.25f * (xp[4*s] + xp[4*s+1] + xp[4*s+2] + xp[4*s+3]);
    __shared__ float smn[kS], smx[kS];
    smn[s] = v; smx[s] = v;
    __syncthreads();
    for (int off = kS/2; off > 0; off >>= 1) {
        if (s < off) {
            smn[s] = fminf(smn[s], smn[s+off]);
            smx[s] = fmaxf(smx[s], smx[s+off]);
        }
        __syncthreads();
    }
    float mn = smn[0], mx = smx[0];
    float xv = 2.0f * (v - mn) / (mx - mn + kEps) - 1.0f;
    xv = fminf(fmaxf(xv, -1.0f), 1.0f);
    float sv = sqrtf(fminf(fmaxf(1.0f - xv*xv, 0.0f), 1.0f));
    xn[bc*kS + s] = xv;
    sq[bc*kS + s] = sv;
}

// ---- conv1: GAF computed on the fly (2 in-ch: gasf, gadf), 128->64, out bf16 ----
// SAME w/ stride2,k3,even H: pad_lo=0, pad_hi=1 -> iy = 2*oy+ky, valid iff iy < HIN.
// Zero padding == both GAF terms zero, so masked taps use xn=sq=0.
__global__ void conv1_gaf_kernel(const float* __restrict__ xn, const float* __restrict__ sq,
                                 const float* __restrict__ w, const float* __restrict__ bias,
                                 __hip_bfloat16* __restrict__ out, int img0, int nimg) {
    constexpr int HOUT = 64, COUT = 32;
    int total = nimg * COUT * HOUT * HOUT;
    int idx = blockIdx.x * blockDim.x + threadIdx.x;
    if (idx >= total) return;
    int ox = idx % HOUT;
    int oy = (idx / HOUT) % HOUT;
    int oc = (idx / (HOUT*HOUT)) % COUT;
    int nl = idx / (HOUT*HOUT*COUT);
    int bc = img0 + nl;
    const float* xv = xn + (size_t)bc * kS;
    const float* sv = sq + (size_t)bc * kS;
    float xr[3], sr[3], xc[3], sc[3];
    int iy0 = oy*2, ix0 = ox*2;
    #pragma unroll
    for (int k = 0; k < 3; ++k) {
        int iy = iy0 + k, ix = ix0 + k;
        bool vy = iy < kS, vx = ix < kS;
        xr[k] = vy ? xv[iy] : 0.0f;  sr[k] = vy ? sv[iy] : 0.0f;
        xc[k] = vx ? xv[ix] : 0.0f;  sc[k] = vx ? sv[ix] : 0.0f;
    }
    const float* wp = w + (size_t)oc * 18;   // (oc, 2, 3, 3)
    float acc = bias[oc];
    #pragma unroll
    for (int ky = 0; ky < 3; ++ky) {
        #pragma unroll
        for (int kx = 0; kx < 3; ++kx) {
            float g0 = xr[ky]*xc[kx] - sr[ky]*sc[kx];   // gasf
            float g1 = sr[ky]*xc[kx] - xr[ky]*sc[kx];   // gadf
            acc = fmaf(g0, wp[ky*3+kx], acc);
            acc = fmaf(g1, wp[9+ky*3+kx], acc);
        }
    }
    out[(size_t)idx] = __float2bfloat16(fmaxf(acc, 0.0f));
}

// ---- generic direct 3x3 stride-2 SAME conv + bias + relu (chunked batch) ----
template<typename Tin, typename Tout, int CIN, int COUT, int HIN>
__global__ void conv_relu_kernel(const Tin* __restrict__ in, const float* __restrict__ w,
                                 const float* __restrict__ bias, Tout* __restrict__ out,
                                 int nimg) {
    constexpr int HOUT = HIN / 2;
    int total = nimg * COUT * HOUT * HOUT;
    int idx = blockIdx.x * blockDim.x + threadIdx.x;
    if (idx >= total) return;
    int ox = idx % HOUT;
    int oy = (idx / HOUT) % HOUT;
    int oc = (idx / (HOUT*HOUT)) % COUT;
    int n  = idx / (HOUT*HOUT*COUT);
    float acc = bias[oc];
    const Tin* inp = in + (size_t)n * CIN * HIN * HIN;
    const float* wp = w + (size_t)oc * CIN * 9;
    int iy0 = oy*2, ix0 = ox*2;
    for (int ic = 0; ic < CIN; ++ic) {
        const Tin* ip = inp + (size_t)ic * HIN * HIN;
        const float* wq = wp + ic*9;
        #pragma unroll
        for (int ky = 0; ky < 3; ++ky) {
            int iy = iy0 + ky;
            if (iy < HIN) {
                #pragma unroll
                for (int kx = 0; kx < 3; ++kx) {
                    int ix = ix0 + kx;
                    if (ix < HIN)
                        acc = fmaf(ldf(ip, (size_t)iy*HIN + ix), wq[ky*3+kx], acc);
                }
            }
        }
    }
    stf(out, (size_t)idx, fmaxf(acc, 0.0f));
}

// ---- global avg pool (8x8) + FC 256->128, per image ----
__global__ void pool_fc_kernel(const float* __restrict__ h4, const float* __restrict__ Wfc,
                               const float* __restrict__ bfc, float* __restrict__ z) {
    int n = blockIdx.x;    // nimg (chunk)
    int t = threadIdx.x;   // 256
    __shared__ float pooled[256];
    const float* hp = h4 + (size_t)n * 256 * 64 + (size_t)t * 64;
    float s = 0.0f;
    #pragma unroll
    for (int i = 0; i < 64; ++i) s += hp[i];
    pooled[t] = s * (1.0f/64.0f);
    __syncthreads();
    if (t < kLatent) {
        float acc = bfc[t];
        for (int k = 0; k < 256; ++k) acc = fmaf(pooled[k], Wfc[(size_t)k*kLatent + t], acc);
        z[(size_t)n*kLatent + t] = acc;
    }
}

// ---- mean over the 32 channel-images ----
__global__ void final_mean_kernel(const float* __restrict__ z, float* __restrict__ out) {
    int b = blockIdx.x;    // 16
    int l = threadIdx.x;   // 128
    float s = 0.0f;
    #pragma unroll
    for (int c = 0; c < kC; ++c) s += z[((size_t)(b*kC + c))*kLatent + l];
    out[(size_t)b*kLatent + l] = s * (1.0f/kC);
}

extern "C" void kernel_launch(void* const* d_in, const int* in_sizes, int n_in,
                              void* d_out, int out_size, void* d_ws, size_t ws_size,
                              hipStream_t stream) {
    const float* x_raw = (const float*)d_in[0];
    const float* W1 = (const float*)d_in[1];  const float* b1 = (const float*)d_in[2];
    const float* W2 = (const float*)d_in[3];  const float* b2 = (const float*)d_in[4];
    const float* W3 = (const float*)d_in[5];  const float* b3 = (const float*)d_in[6];
    const float* W4 = (const float*)d_in[7];  const float* b4 = (const float*)d_in[8];
    const float* Wfc = (const float*)d_in[9]; const float* bfc = (const float*)d_in[10];
    float* out = (float*)d_out;

    // Small persistent buffers in first 1 MiB: xn, sq, z
    char* wsb = (char*)d_ws;
    float* xn = (float*)wsb;                       // 256 KiB
    float* sq = (float*)(wsb + (256u << 10));      // 256 KiB
    float* z  = (float*)(wsb + (512u << 10));      // 256 KiB
    char* chunk_base = wsb + (1u << 20);

    // Per-image chunk footprint: region A (h1 bf16 / h3 f32): 256 KiB,
    // region B (h2 f32 / h4 f32): 256 KiB. Pick the largest chunk that fits.
    const size_t perImgA = 32u * 64u * 64u * 2u;   // 256 KiB (h1 bf16; h3 f32 = 128 KiB fits)
    const size_t perImgB = 64u * 32u * 32u * 4u;   // 256 KiB (h2 f32; h4 f32 = 64 KiB fits)
    int chunk = 8;
    for (int c = 512; c >= 8; c >>= 1) {
        size_t need = (1u << 20) + (size_t)c * (perImgA + perImgB);
        if (need <= ws_size) { chunk = c; break; }
    }

    gaf_stats_kernel<<<kBC, kS, 0, stream>>>(x_raw, xn, sq);

    for (int img0 = 0; img0 < kBC; img0 += chunk) {
        int nimg = chunk;  // 512 % chunk == 0 for power-of-2 chunks
        char* A = chunk_base;
        char* Bp = chunk_base + (size_t)chunk * perImgA;
        __hip_bfloat16* h1 = (__hip_bfloat16*)A;
        float* h2 = (float*)Bp;
        float* h3 = (float*)A;
        float* h4 = (float*)Bp;

        {   // conv1 (GAF on the fly): 2->32, 128->64
            int total = nimg * 32 * 64 * 64;
            conv1_gaf_kernel<<<(total + 255) / 256, 256, 0, stream>>>(
                xn, sq, W1, b1, h1, img0, nimg);
        }
        {   // conv2: 32->64, 64->32
            int total = nimg * 64 * 32 * 32;
            conv_relu_kernel<__hip_bfloat16, float, 32, 64, 64>
                <<<(total + 255) / 256, 256, 0, stream>>>(h1, W2, b2, h2, nimg);
        }
        {   // conv3: 64->128, 32->16
            int total = nimg * 128 * 16 * 16;
            conv_relu_kernel<float, float, 64, 128, 32>
                <<<(total + 255) / 256, 256, 0, stream>>>(h2, W3, b3, h3, nimg);
        }
        {   // conv4: 128->256, 16->8
            int total = nimg * 256 * 8 * 8;
            conv_relu_kernel<float, float, 128, 256, 16>
                <<<(total + 255) / 256, 256, 0, stream>>>(h3, W4, b4, h4, nimg);
        }
        pool_fc_kernel<<<nimg, 256, 0, stream>>>(h4, Wfc, bfc, z + (size_t)img0 * kLatent);
    }

    final_mean_kernel<<<kB, kLatent, 0, stream>>>(z, out);
}

// Round 3
// 550.956 us; speedup vs baseline: 25.5346x; 25.5346x over previous
//
#include <hip/hip_runtime.h>
#include <hip/hip_bf16.h>

#define DEV __device__ __forceinline__

constexpr int kB = 16, kC = 32, kT = 512, kS = 128, kBC = 512, kLatent = 128;
constexpr float kEps = 1e-8f;

using bf16 = __hip_bfloat16;
using bf16x8 = __attribute__((ext_vector_type(8))) short;   // 8 bf16 = 4 VGPRs
using f32x4  = __attribute__((ext_vector_type(4))) float;

// ---- Kernel 1: per-(b,c) downsample + min/max normalize + sqrt term ----
__global__ void gaf_stats_kernel(const float* __restrict__ x_raw,
                                 float* __restrict__ xn, float* __restrict__ sq) {
    int bc = blockIdx.x;       // 512
    int s  = threadIdx.x;      // 128
    const float* xp = x_raw + (size_t)bc * kT;
    float v = 0.25f * (xp[4*s] + xp[4*s+1] + xp[4*s+2] + xp[4*s+3]);
    __shared__ float smn[kS], smx[kS];
    smn[s] = v; smx[s] = v;
    __syncthreads();
    for (int off = kS/2; off > 0; off >>= 1) {
        if (s < off) {
            smn[s] = fminf(smn[s], smn[s+off]);
            smx[s] = fmaxf(smx[s], smx[s+off]);
        }
        __syncthreads();
    }
    float mn = smn[0], mx = smx[0];
    float xv = 2.0f * (v - mn) / (mx - mn + kEps) - 1.0f;
    xv = fminf(fmaxf(xv, -1.0f), 1.0f);
    float sv = sqrtf(fminf(fmaxf(1.0f - xv*xv, 0.0f), 1.0f));
    xn[bc*kS + s] = xv;
    sq[bc*kS + s] = sv;
}

// ---- weight transpose: OIHW f32 -> [tap][oc][ic] bf16 ----
__global__ void wtrans_kernel(const float* __restrict__ w, bf16* __restrict__ wt,
                              int COUT, int CIN) {
    int total = 9 * COUT * CIN;
    int idx = blockIdx.x * blockDim.x + threadIdx.x;
    if (idx >= total) return;
    int ic = idx % CIN;
    int oc = (idx / CIN) % COUT;
    int t  = idx / (CIN * COUT);
    wt[((size_t)t * COUT + oc) * CIN + ic] = __float2bfloat16(w[((size_t)oc * CIN + ic) * 9 + t]);
}

// ---- conv1: GAF on the fly (2 in-ch), 128->64, out NHWC bf16 [n][64][64][32] ----
// SAME w/ stride2,k3,even H: pad_lo=0, pad_hi=1 -> valid iff iy < HIN.
__global__ void conv1_gaf_kernel(const float* __restrict__ xn, const float* __restrict__ sq,
                                 const float* __restrict__ w, const float* __restrict__ bias,
                                 bf16* __restrict__ out, int img0, int nimg) {
    constexpr int HOUT = 64, COUT = 32;
    int total = nimg * HOUT * HOUT * COUT;   // oc fastest
    int idx = blockIdx.x * blockDim.x + threadIdx.x;
    if (idx >= total) return;
    int oc = idx & 31;
    int rest = idx >> 5;
    int ox = rest & 63;
    int oy = (rest >> 6) & 63;
    int nl = idx >> 17;
    int bc = img0 + nl;
    const float* xv = xn + (size_t)bc * kS;
    const float* sv = sq + (size_t)bc * kS;
    float xr[3], sr[3], xc[3], sc[3];
    int iy0 = oy*2, ix0 = ox*2;
    #pragma unroll
    for (int k = 0; k < 3; ++k) {
        int iy = iy0 + k, ix = ix0 + k;
        bool vy = iy < kS, vx = ix < kS;
        xr[k] = vy ? xv[iy] : 0.0f;  sr[k] = vy ? sv[iy] : 0.0f;
        xc[k] = vx ? xv[ix] : 0.0f;  sc[k] = vx ? sv[ix] : 0.0f;
    }
    const float* wp = w + (size_t)oc * 18;   // (oc, 2, 3, 3)
    float acc = bias[oc];
    #pragma unroll
    for (int ky = 0; ky < 3; ++ky) {
        #pragma unroll
        for (int kx = 0; kx < 3; ++kx) {
            float g0 = xr[ky]*xc[kx] - sr[ky]*sc[kx];   // gasf
            float g1 = sr[ky]*xc[kx] - xr[ky]*sc[kx];   // gadf
            acc = fmaf(g0, wp[ky*3+kx], acc);
            acc = fmaf(g1, wp[9+ky*3+kx], acc);
        }
    }
    out[(size_t)idx] = __float2bfloat16(fmaxf(acc, 0.0f));
}

// ---- MFMA implicit-GEMM 3x3 stride-2 SAME conv, NHWC bf16 ----
// A: M=64 output positions x K=32 (one tap's ic slice); B: 64 oc x 32 ic.
// Wave w computes 16M x 64N via 4 MFMA 16x16x32 tiles.
// POOL: fuse global-avg-pool (relu -> sum over all positions) into epilogue.
template<int CIN, int COUT, int HIN, bool POOL>
__global__ __launch_bounds__(256)
void conv_mfma_kernel(const bf16* __restrict__ in, const bf16* __restrict__ wt,
                      const float* __restrict__ bias, bf16* __restrict__ out,
                      float* __restrict__ pooled, int img0) {
    constexpr int HOUT = HIN / 2;
    constexpr int KSTEPS = CIN / 32;
    __shared__ short As[64][40];   // 64 rows x 32 bf16, stride 40 (80 B) anti-conflict
    __shared__ short Bs[64][40];
    __shared__ float partial[4][64];

    int tid  = threadIdx.x;
    int lane = tid & 63;
    int wv   = tid >> 6;
    int mblk = blockIdx.x;
    int nblk = blockIdx.y;
    int n    = blockIdx.z;   // chunk-local image

    f32x4 acc[4];
    #pragma unroll
    for (int i = 0; i < 4; ++i) acc[i] = f32x4{0.f, 0.f, 0.f, 0.f};

    int r = tid >> 2, p = tid & 3;           // staging: 4 threads per row, 16 B each
    int pos_s = mblk*64 + r;
    int oy_s = pos_s / HOUT, ox_s = pos_s % HOUT;

    for (int tap = 0; tap < 9; ++tap) {
        int ky = tap / 3, kx = tap % 3;
        int iy = 2*oy_s + ky, ix = 2*ox_s + kx;
        bool valid = (iy < HIN) && (ix < HIN);
        const bf16* arow = in + (((size_t)n*HIN + iy)*HIN + ix)*CIN;
        const bf16* brow = wt + ((size_t)tap*COUT + nblk*64 + r)*CIN;
        for (int ks = 0; ks < KSTEPS; ++ks) {
            uint4 av = {0u,0u,0u,0u};
            if (valid) av = *(const uint4*)(arow + ks*32 + p*8);
            *(uint4*)&As[r][p*8] = av;
            *(uint4*)&Bs[r][p*8] = *(const uint4*)(brow + ks*32 + p*8);
            __syncthreads();
            bf16x8 afrag = *(const bf16x8*)&As[wv*16 + (lane&15)][(lane>>4)*8];
            #pragma unroll
            for (int nt = 0; nt < 4; ++nt) {
                bf16x8 bfrag = *(const bf16x8*)&Bs[nt*16 + (lane&15)][(lane>>4)*8];
                acc[nt] = __builtin_amdgcn_mfma_f32_16x16x32_bf16(afrag, bfrag, acc[nt], 0, 0, 0);
            }
            __syncthreads();
        }
    }

    // Epilogue. C/D layout: col = lane&15, row = (lane>>4)*4 + reg.
    if (!POOL) {
        #pragma unroll
        for (int nt = 0; nt < 4; ++nt) {
            int oc = nblk*64 + nt*16 + (lane & 15);
            float b = bias[oc];
            #pragma unroll
            for (int rg = 0; rg < 4; ++rg) {
                int row = (lane >> 4) * 4 + rg;
                int pos = mblk*64 + wv*16 + row;
                int oy = pos / HOUT, ox = pos % HOUT;
                float v = fmaxf(acc[nt][rg] + b, 0.0f);
                out[(((size_t)n*HOUT + oy)*HOUT + ox)*COUT + oc] = __float2bfloat16(v);
            }
        }
    } else {
        // relu -> sum over this wave's 16 rows per col, then combine 4 waves.
        #pragma unroll
        for (int nt = 0; nt < 4; ++nt) {
            int oc = nblk*64 + nt*16 + (lane & 15);
            float b = bias[oc];
            float s = 0.0f;
            #pragma unroll
            for (int rg = 0; rg < 4; ++rg) s += fmaxf(acc[nt][rg] + b, 0.0f);
            s += __shfl_xor(s, 16);
            s += __shfl_xor(s, 32);
            if (lane < 16) partial[wv][nt*16 + lane] = s;
        }
        __syncthreads();
        if (tid < 64) {
            float s = partial[0][tid] + partial[1][tid] + partial[2][tid] + partial[3][tid];
            pooled[((size_t)(img0 + n))*256 + nblk*64 + tid] = s * (1.0f/64.0f);
        }
    }
}

// ---- FC 256->128 per image ----
__global__ void fc_kernel(const float* __restrict__ pooled, const float* __restrict__ Wfc,
                          const float* __restrict__ bfc, float* __restrict__ z) {
    int n = blockIdx.x;    // 512
    int t = threadIdx.x;   // 128
    const float* hp = pooled + (size_t)n * 256;
    float acc = bfc[t];
    for (int k = 0; k < 256; ++k) acc = fmaf(hp[k], Wfc[(size_t)k*kLatent + t], acc);
    z[(size_t)n*kLatent + t] = acc;
}

// ---- mean over the 32 channel-images ----
__global__ void final_mean_kernel(const float* __restrict__ z, float* __restrict__ out) {
    int b = blockIdx.x;    // 16
    int l = threadIdx.x;   // 128
    float s = 0.0f;
    #pragma unroll
    for (int c = 0; c < kC; ++c) s += z[((size_t)(b*kC + c))*kLatent + l];
    out[(size_t)b*kLatent + l] = s * (1.0f/kC);
}

extern "C" void kernel_launch(void* const* d_in, const int* in_sizes, int n_in,
                              void* d_out, int out_size, void* d_ws, size_t ws_size,
                              hipStream_t stream) {
    const float* x_raw = (const float*)d_in[0];
    const float* W1 = (const float*)d_in[1];  const float* b1 = (const float*)d_in[2];
    const float* W2 = (const float*)d_in[3];  const float* b2 = (const float*)d_in[4];
    const float* W3 = (const float*)d_in[5];  const float* b3 = (const float*)d_in[6];
    const float* W4 = (const float*)d_in[7];  const float* b4 = (const float*)d_in[8];
    const float* Wfc = (const float*)d_in[9]; const float* bfc = (const float*)d_in[10];
    float* out = (float*)d_out;

    // Workspace layout (all offsets 16B-aligned):
    char* wsb = (char*)d_ws;
    float* xn     = (float*)(wsb);                      // 256 KiB
    float* sq     = (float*)(wsb + (256u<<10));         // 256 KiB
    float* z      = (float*)(wsb + (512u<<10));         // 256 KiB
    float* pooled = (float*)(wsb + (768u<<10));         // 512 KiB
    bf16* Wt2     = (bf16*)(wsb + (1280u<<10));         // 9*64*32*2   = 36 KiB
    bf16* Wt3     = (bf16*)(wsb + (1316u<<10));         // 9*128*64*2  = 144 KiB
    bf16* Wt4     = (bf16*)(wsb + (1460u<<10));         // 9*256*128*2 = 576 KiB
    char* chunk_base = wsb + (2048u<<10);               // 2 MiB header

    // Per-image NHWC bf16 activations: h1 256K, h2 128K, h3 64K = 448 KiB
    const size_t perH1 = 64u*64u*32u*2u, perH2 = 32u*32u*64u*2u, perH3 = 16u*16u*128u*2u;
    const size_t perImg = perH1 + perH2 + perH3;
    int chunk = 4;
    for (int c = 512; c >= 4; c >>= 1) {
        if ((2048u<<10) + (size_t)c * perImg <= ws_size) { chunk = c; break; }
    }

    gaf_stats_kernel<<<kBC, kS, 0, stream>>>(x_raw, xn, sq);
    wtrans_kernel<<<(9*64*32 + 255)/256, 256, 0, stream>>>(W2, Wt2, 64, 32);
    wtrans_kernel<<<(9*128*64 + 255)/256, 256, 0, stream>>>(W3, Wt3, 128, 64);
    wtrans_kernel<<<(9*256*128 + 255)/256, 256, 0, stream>>>(W4, Wt4, 256, 128);

    for (int img0 = 0; img0 < kBC; img0 += chunk) {
        int nimg = chunk;
        bf16* h1 = (bf16*)chunk_base;
        bf16* h2 = (bf16*)(chunk_base + (size_t)chunk * perH1);
        bf16* h3 = (bf16*)(chunk_base + (size_t)chunk * (perH1 + perH2));

        {   // conv1: 2->32, 128->64, NHWC out
            int total = nimg * 64 * 64 * 32;
            conv1_gaf_kernel<<<(total + 255)/256, 256, 0, stream>>>(xn, sq, W1, b1, h1, img0, nimg);
        }
        // conv2: 32->64, 64->32 : M=1024 (16 mblk), N=64 (1 nblk)
        conv_mfma_kernel<32, 64, 64, false>
            <<<dim3(16, 1, nimg), 256, 0, stream>>>(h1, Wt2, b2, h2, nullptr, img0);
        // conv3: 64->128, 32->16 : M=256 (4 mblk), N=128 (2 nblk)
        conv_mfma_kernel<64, 128, 32, false>
            <<<dim3(4, 2, nimg), 256, 0, stream>>>(h2, Wt3, b3, h3, nullptr, img0);
        // conv4: 128->256, 16->8 : M=64 (1 mblk), N=256 (4 nblk), fused pool
        conv_mfma_kernel<128, 256, 16, true>
            <<<dim3(1, 4, nimg), 256, 0, stream>>>(h3, Wt4, b4, nullptr, pooled, img0);
    }

    fc_kernel<<<kBC, kLatent, 0, stream>>>(pooled, Wfc, bfc, z);
    final_mean_kernel<<<kB, kLatent, 0, stream>>>(z, out);
}

// Round 4
// 369.430 us; speedup vs baseline: 38.0815x; 1.4914x over previous
//
#include <hip/hip_runtime.h>
#include <hip/hip_bf16.h>

#define DEV __device__ __forceinline__

constexpr int kB = 16, kC = 32, kT = 512, kS = 128, kBC = 512, kLatent = 128;
constexpr float kEps = 1e-8f;

using bf16 = __hip_bfloat16;
using bf16x8 = __attribute__((ext_vector_type(8))) short;   // 8 bf16 = 4 VGPRs
using f32x4  = __attribute__((ext_vector_type(4))) float;

DEV unsigned short f2bf(float v) {
    bf16 h = __float2bfloat16(v);
    return *(unsigned short*)&h;
}

// ---- Kernel 1: per-(b,c) downsample + min/max normalize + sqrt term ----
__global__ void gaf_stats_kernel(const float* __restrict__ x_raw,
                                 float* __restrict__ xn, float* __restrict__ sq) {
    int bc = blockIdx.x;       // 512
    int s  = threadIdx.x;      // 128
    const float* xp = x_raw + (size_t)bc * kT;
    float v = 0.25f * (xp[4*s] + xp[4*s+1] + xp[4*s+2] + xp[4*s+3]);
    __shared__ float smn[kS], smx[kS];
    smn[s] = v; smx[s] = v;
    __syncthreads();
    for (int off = kS/2; off > 0; off >>= 1) {
        if (s < off) {
            smn[s] = fminf(smn[s], smn[s+off]);
            smx[s] = fmaxf(smx[s], smx[s+off]);
        }
        __syncthreads();
    }
    float mn = smn[0], mx = smx[0];
    float xv = 2.0f * (v - mn) / (mx - mn + kEps) - 1.0f;
    xv = fminf(fmaxf(xv, -1.0f), 1.0f);
    float sv = sqrtf(fminf(fmaxf(1.0f - xv*xv, 0.0f), 1.0f));
    xn[bc*kS + s] = xv;
    sq[bc*kS + s] = sv;
}

// ---- weight transpose: OIHW f32 -> [tap][oc][ic] bf16 ----
__global__ void wtrans_kernel(const float* __restrict__ w, bf16* __restrict__ wt,
                              int COUT, int CIN) {
    int total = 9 * COUT * CIN;
    int idx = blockIdx.x * blockDim.x + threadIdx.x;
    if (idx >= total) return;
    int ic = idx % CIN;
    int oc = (idx / CIN) % COUT;
    int t  = idx / (CIN * COUT);
    wt[((size_t)t * COUT + oc) * CIN + ic] = __float2bfloat16(w[((size_t)oc * CIN + ic) * 9 + t]);
}

// ---- conv1: thread-per-position, all 32 oc; GAF from LDS; scalar weights ----
// out NHWC bf16 [n][64][64][32]. SAME stride2 k3: valid iff iy < 128.
__global__ __launch_bounds__(256)
void conv1_gaf_kernel(const float* __restrict__ xn, const float* __restrict__ sq,
                      const float* __restrict__ w, const float* __restrict__ bias,
                      bf16* __restrict__ out, int img0) {
    int bc = img0 + blockIdx.y;           // absolute image for xn/sq
    int tid = threadIdx.x;
    int oy = blockIdx.x * 4 + (tid >> 6); // 4 rows per block
    int ox = tid & 63;
    __shared__ float xl[kS], sl[kS];
    if (tid < 128) xl[tid] = xn[(size_t)bc * kS + tid];
    else           sl[tid - 128] = sq[(size_t)bc * kS + (tid - 128)];
    __syncthreads();

    float xr[3], sr[3], xc[3], sc[3];
    #pragma unroll
    for (int k = 0; k < 3; ++k) {
        int iy = 2*oy + k, ix = 2*ox + k;
        bool vy = iy < kS, vx = ix < kS;
        xr[k] = vy ? xl[iy] : 0.0f;  sr[k] = vy ? sl[iy] : 0.0f;
        xc[k] = vx ? xl[ix] : 0.0f;  sc[k] = vx ? sl[ix] : 0.0f;
    }
    float g0[9], g1[9];
    #pragma unroll
    for (int ky = 0; ky < 3; ++ky) {
        #pragma unroll
        for (int kx = 0; kx < 3; ++kx) {
            g0[ky*3+kx] = xr[ky]*xc[kx] - sr[ky]*sc[kx];
            g1[ky*3+kx] = sr[ky]*xc[kx] - xr[ky]*sc[kx];
        }
    }
    unsigned int pk[16];
    #pragma unroll
    for (int oc = 0; oc < 32; ++oc) {
        const float* wr = w + oc*18;      // uniform -> s_load
        float acc = bias[oc];
        #pragma unroll
        for (int t = 0; t < 9; ++t) {
            acc = fmaf(g0[t], wr[t],   acc);
            acc = fmaf(g1[t], wr[9+t], acc);
        }
        unsigned int b = f2bf(fmaxf(acc, 0.0f));
        if (oc & 1) pk[oc >> 1] |= b << 16;
        else        pk[oc >> 1]  = b;
    }
    uint4* op = (uint4*)(out + (((size_t)blockIdx.y * 64 + oy) * 64 + ox) * 32);
    #pragma unroll
    for (int i = 0; i < 4; ++i) op[i] = ((uint4*)pk)[i];
}

// ---- MFMA implicit-GEMM 3x3 stride-2 SAME conv, NHWC bf16 ----
// Block: 256 M-rows x 64 N-cols, 4 waves, each wave 64Mx64N = 4x4 MFMA tiles.
// IMGS images per block (conv4 batches 4). POOL fuses global-avg-pool.
template<int CIN, int COUT, int HIN, int IMGS, bool POOL>
__global__ __launch_bounds__(256)
void conv_mfma_kernel(const bf16* __restrict__ in, const bf16* __restrict__ wt,
                      const float* __restrict__ bias, bf16* __restrict__ out,
                      float* __restrict__ pooled, int img0) {
    constexpr int HOUT = HIN / 2;
    constexpr int PPI  = HOUT * HOUT;
    constexpr int KSTEPS = CIN / 32;
    __shared__ short As[256][40];   // stride 40 shorts = 80 B (16B-aligned, anti-conflict)
    __shared__ short Bs[64][40];

    int tid  = threadIdx.x;
    int lane = tid & 63;
    int wv   = tid >> 6;
    int nblk = blockIdx.y;

    // staging: thread t owns A-row t
    int r = tid;
    int img_l, pos;
    if (IMGS > 1) { img_l = blockIdx.z * IMGS + r / PPI; pos = r % PPI; }
    else          { img_l = blockIdx.z; pos = (PPI > 256 ? blockIdx.x * 256 + r : r); }
    int oy_s = pos / HOUT, ox_s = pos % HOUT;

    f32x4 acc[4][4];
    #pragma unroll
    for (int i = 0; i < 4; ++i)
        #pragma unroll
        for (int j = 0; j < 4; ++j) acc[i][j] = f32x4{0.f, 0.f, 0.f, 0.f};

    int brow_i = tid >> 2, bseg = tid & 3;
    for (int tap = 0; tap < 9; ++tap) {
        int ky = tap / 3, kx = tap % 3;
        int iy = 2*oy_s + ky, ix = 2*ox_s + kx;
        bool valid = (iy < HIN) && (ix < HIN);
        const bf16* arow = in + (((size_t)img_l * HIN + iy) * HIN + ix) * CIN;
        const bf16* brow = wt + ((size_t)tap * COUT + nblk*64 + brow_i) * CIN + bseg*8;
        for (int ks = 0; ks < KSTEPS; ++ks) {
            #pragma unroll
            for (int seg = 0; seg < 4; ++seg) {
                uint4 av = {0u, 0u, 0u, 0u};
                if (valid) av = *(const uint4*)(arow + ks*32 + seg*8);
                *(uint4*)&As[r][seg*8] = av;
            }
            *(uint4*)&Bs[brow_i][bseg*8] = *(const uint4*)(brow + ks*32);
            __syncthreads();
            bf16x8 af[4], bfr[4];
            #pragma unroll
            for (int mi = 0; mi < 4; ++mi)
                af[mi] = *(const bf16x8*)&As[wv*64 + mi*16 + (lane&15)][(lane>>4)*8];
            #pragma unroll
            for (int ni = 0; ni < 4; ++ni)
                bfr[ni] = *(const bf16x8*)&Bs[ni*16 + (lane&15)][(lane>>4)*8];
            #pragma unroll
            for (int mi = 0; mi < 4; ++mi)
                #pragma unroll
                for (int ni = 0; ni < 4; ++ni)
                    acc[mi][ni] = __builtin_amdgcn_mfma_f32_16x16x32_bf16(af[mi], bfr[ni], acc[mi][ni], 0, 0, 0);
            __syncthreads();
        }
    }

    // Epilogue. C/D layout: col = lane&15 (N), row = (lane>>4)*4 + rg (M).
    if (!POOL) {
        #pragma unroll
        for (int ni = 0; ni < 4; ++ni) {
            int oc = nblk*64 + ni*16 + (lane & 15);
            float b = bias[oc];
            #pragma unroll
            for (int mi = 0; mi < 4; ++mi) {
                #pragma unroll
                for (int rg = 0; rg < 4; ++rg) {
                    int rr = wv*64 + mi*16 + (lane>>4)*4 + rg;
                    int img_e, pos_e;
                    if (IMGS > 1) { img_e = blockIdx.z*IMGS + rr/PPI; pos_e = rr % PPI; }
                    else { img_e = blockIdx.z; pos_e = (PPI > 256 ? blockIdx.x*256 + rr : rr); }
                    int oy = pos_e / HOUT, ox = pos_e % HOUT;
                    float v = fmaxf(acc[mi][ni][rg] + b, 0.0f);
                    out[(((size_t)img_e * HOUT + oy) * HOUT + ox) * COUT + oc] = __float2bfloat16(v);
                }
            }
        }
    } else {
        // wave wv == image blockIdx.z*IMGS + wv (its 64 M-rows are that image's 8x8 grid)
        int img_e = blockIdx.z * IMGS + wv;
        #pragma unroll
        for (int ni = 0; ni < 4; ++ni) {
            int oc = nblk*64 + ni*16 + (lane & 15);
            float b = bias[oc];
            float s = 0.0f;
            #pragma unroll
            for (int mi = 0; mi < 4; ++mi)
                #pragma unroll
                for (int rg = 0; rg < 4; ++rg) s += fmaxf(acc[mi][ni][rg] + b, 0.0f);
            s += __shfl_xor(s, 16);
            s += __shfl_xor(s, 32);
            if (lane < 16)
                pooled[((size_t)(img0 + img_e)) * 256 + nblk*64 + ni*16 + lane] = s * (1.0f/64.0f);
        }
    }
}

// ---- FC 256->128 per image ----
__global__ void fc_kernel(const float* __restrict__ pooled, const float* __restrict__ Wfc,
                          const float* __restrict__ bfc, float* __restrict__ z) {
    int n = blockIdx.x;    // 512
    int t = threadIdx.x;   // 128
    const float* hp = pooled + (size_t)n * 256;
    float acc = bfc[t];
    for (int k = 0; k < 256; ++k) acc = fmaf(hp[k], Wfc[(size_t)k*kLatent + t], acc);
    z[(size_t)n*kLatent + t] = acc;
}

// ---- mean over the 32 channel-images ----
__global__ void final_mean_kernel(const float* __restrict__ z, float* __restrict__ out) {
    int b = blockIdx.x;    // 16
    int l = threadIdx.x;   // 128
    float s = 0.0f;
    #pragma unroll
    for (int c = 0; c < kC; ++c) s += z[((size_t)(b*kC + c))*kLatent + l];
    out[(size_t)b*kLatent + l] = s * (1.0f/kC);
}

extern "C" void kernel_launch(void* const* d_in, const int* in_sizes, int n_in,
                              void* d_out, int out_size, void* d_ws, size_t ws_size,
                              hipStream_t stream) {
    const float* x_raw = (const float*)d_in[0];
    const float* W1 = (const float*)d_in[1];  const float* b1 = (const float*)d_in[2];
    const float* W2 = (const float*)d_in[3];  const float* b2 = (const float*)d_in[4];
    const float* W3 = (const float*)d_in[5];  const float* b3 = (const float*)d_in[6];
    const float* W4 = (const float*)d_in[7];  const float* b4 = (const float*)d_in[8];
    const float* Wfc = (const float*)d_in[9]; const float* bfc = (const float*)d_in[10];
    float* out = (float*)d_out;

    char* wsb = (char*)d_ws;
    float* xn     = (float*)(wsb);                      // 256 KiB
    float* sq     = (float*)(wsb + (256u<<10));         // 256 KiB
    float* z      = (float*)(wsb + (512u<<10));         // 256 KiB
    float* pooled = (float*)(wsb + (768u<<10));         // 512 KiB
    bf16* Wt2     = (bf16*)(wsb + (1280u<<10));         // 36 KiB
    bf16* Wt3     = (bf16*)(wsb + (1316u<<10));         // 144 KiB
    bf16* Wt4     = (bf16*)(wsb + (1460u<<10));         // 576 KiB
    char* chunk_base = wsb + (2048u<<10);               // 2 MiB header

    const size_t perH1 = 64u*64u*32u*2u, perH2 = 32u*32u*64u*2u, perH3 = 16u*16u*128u*2u;
    const size_t perImg = perH1 + perH2 + perH3;
    int chunk = 4;
    for (int c = 512; c >= 4; c >>= 1) {
        if ((2048u<<10) + (size_t)c * perImg <= ws_size) { chunk = c; break; }
    }

    gaf_stats_kernel<<<kBC, kS, 0, stream>>>(x_raw, xn, sq);
    wtrans_kernel<<<(9*64*32 + 255)/256, 256, 0, stream>>>(W2, Wt2, 64, 32);
    wtrans_kernel<<<(9*128*64 + 255)/256, 256, 0, stream>>>(W3, Wt3, 128, 64);
    wtrans_kernel<<<(9*256*128 + 255)/256, 256, 0, stream>>>(W4, Wt4, 256, 128);

    for (int img0 = 0; img0 < kBC; img0 += chunk) {
        int nimg = chunk;
        bf16* h1 = (bf16*)chunk_base;
        bf16* h2 = (bf16*)(chunk_base + (size_t)chunk * perH1);
        bf16* h3 = (bf16*)(chunk_base + (size_t)chunk * (perH1 + perH2));

        // conv1: 2->32, 128->64
        conv1_gaf_kernel<<<dim3(16, nimg), 256, 0, stream>>>(xn, sq, W1, b1, h1, img0);
        // conv2: 32->64, 64->32 : M=1024/img -> 4 mblk, N=64
        conv_mfma_kernel<32, 64, 64, 1, false>
            <<<dim3(4, 1, nimg), 256, 0, stream>>>(h1, Wt2, b2, h2, nullptr, img0);
        // conv3: 64->128, 32->16 : M=256/img -> 1 mblk, N=128 -> 2 nblk
        conv_mfma_kernel<64, 128, 32, 1, false>
            <<<dim3(1, 2, nimg), 256, 0, stream>>>(h2, Wt3, b3, h3, nullptr, img0);
        // conv4: 128->256, 16->8 : 4 imgs/block (M=256), N=256 -> 4 nblk, fused pool
        conv_mfma_kernel<128, 256, 16, 4, true>
            <<<dim3(1, 4, nimg/4), 256, 0, stream>>>(h3, Wt4, b4, nullptr, pooled, img0);
    }

    fc_kernel<<<kBC, kLatent, 0, stream>>>(pooled, Wfc, bfc, z);
    final_mean_kernel<<<kB, kLatent, 0, stream>>>(z, out);
}

// Round 5
// 324.688 us; speedup vs baseline: 43.3291x; 1.1378x over previous
//
#include <hip/hip_runtime.h>
#include <hip/hip_bf16.h>

#define DEV __device__ __forceinline__

constexpr int kB = 16, kC = 32, kT = 512, kS = 128, kBC = 512, kLatent = 128;
constexpr float kEps = 1e-8f;

using bf16 = __hip_bfloat16;
using bf16x8 = __attribute__((ext_vector_type(8))) short;   // 8 bf16 = 4 VGPRs
using f32x4  = __attribute__((ext_vector_type(4))) float;

DEV unsigned short f2bf(float v) {
    bf16 h = __float2bfloat16(v);
    return *(unsigned short*)&h;
}

// ---- Kernel 1: per-(b,c) downsample + min/max normalize + sqrt term ----
__global__ void gaf_stats_kernel(const float* __restrict__ x_raw,
                                 float* __restrict__ xn, float* __restrict__ sq) {
    int bc = blockIdx.x;       // 512
    int s  = threadIdx.x;      // 128
    const float* xp = x_raw + (size_t)bc * kT;
    float v = 0.25f * (xp[4*s] + xp[4*s+1] + xp[4*s+2] + xp[4*s+3]);
    __shared__ float smn[kS], smx[kS];
    smn[s] = v; smx[s] = v;
    __syncthreads();
    for (int off = kS/2; off > 0; off >>= 1) {
        if (s < off) {
            smn[s] = fminf(smn[s], smn[s+off]);
            smx[s] = fmaxf(smx[s], smx[s+off]);
        }
        __syncthreads();
    }
    float mn = smn[0], mx = smx[0];
    float xv = 2.0f * (v - mn) / (mx - mn + kEps) - 1.0f;
    xv = fminf(fmaxf(xv, -1.0f), 1.0f);
    float sv = sqrtf(fminf(fmaxf(1.0f - xv*xv, 0.0f), 1.0f));
    xn[bc*kS + s] = xv;
    sq[bc*kS + s] = sv;
}

// ---- weight transpose: OIHW f32 -> [tap][oc][ic] bf16 ----
__global__ void wtrans_kernel(const float* __restrict__ w, bf16* __restrict__ wt,
                              int COUT, int CIN) {
    int total = 9 * COUT * CIN;
    int idx = blockIdx.x * blockDim.x + threadIdx.x;
    if (idx >= total) return;
    int ic = idx % CIN;
    int oc = (idx / CIN) % COUT;
    int t  = idx / (CIN * COUT);
    wt[((size_t)t * COUT + oc) * CIN + ic] = __float2bfloat16(w[((size_t)oc * CIN + ic) * 9 + t]);
}

// ---- conv1: thread-per-position, all 32 oc; GAF from LDS; scalar weights ----
// out NHWC bf16 [n][64][64][32]. SAME stride2 k3: valid iff iy < 128.
__global__ __launch_bounds__(256)
void conv1_gaf_kernel(const float* __restrict__ xn, const float* __restrict__ sq,
                      const float* __restrict__ w, const float* __restrict__ bias,
                      bf16* __restrict__ out, int img0) {
    int bc = img0 + blockIdx.y;           // absolute image for xn/sq
    int tid = threadIdx.x;
    int oy = blockIdx.x * 4 + (tid >> 6); // 4 rows per block
    int ox = tid & 63;
    __shared__ float xl[kS], sl[kS];
    if (tid < 128) xl[tid] = xn[(size_t)bc * kS + tid];
    else           sl[tid - 128] = sq[(size_t)bc * kS + (tid - 128)];
    __syncthreads();

    float xr[3], sr[3], xc[3], sc[3];
    #pragma unroll
    for (int k = 0; k < 3; ++k) {
        int iy = 2*oy + k, ix = 2*ox + k;
        bool vy = iy < kS, vx = ix < kS;
        xr[k] = vy ? xl[iy] : 0.0f;  sr[k] = vy ? sl[iy] : 0.0f;
        xc[k] = vx ? xl[ix] : 0.0f;  sc[k] = vx ? sl[ix] : 0.0f;
    }
    float g0[9], g1[9];
    #pragma unroll
    for (int ky = 0; ky < 3; ++ky) {
        #pragma unroll
        for (int kx = 0; kx < 3; ++kx) {
            g0[ky*3+kx] = xr[ky]*xc[kx] - sr[ky]*sc[kx];
            g1[ky*3+kx] = sr[ky]*xc[kx] - xr[ky]*sc[kx];
        }
    }
    unsigned int pk[16];
    #pragma unroll
    for (int oc = 0; oc < 32; ++oc) {
        const float* wr = w + oc*18;      // uniform -> s_load
        float acc = bias[oc];
        #pragma unroll
        for (int t = 0; t < 9; ++t) {
            acc = fmaf(g0[t], wr[t],   acc);
            acc = fmaf(g1[t], wr[9+t], acc);
        }
        unsigned int b = f2bf(fmaxf(acc, 0.0f));
        if (oc & 1) pk[oc >> 1] |= b << 16;
        else        pk[oc >> 1]  = b;
    }
    uint4* op = (uint4*)(out + (((size_t)blockIdx.y * 64 + oy) * 64 + ox) * 32);
    #pragma unroll
    for (int i = 0; i < 4; ++i) op[i] = ((uint4*)pk)[i];
}

// ---- MFMA implicit-GEMM conv, m97-style K-loop ----
// Block: 128 M x 64 N. K = 9*CIN flattened (tap-major), BK=64 double-buffered
// stages, ONE barrier per stage; next-stage global loads issued before MFMAs.
// LDS rows padded to 72 shorts (144 B): frag reads & staging writes 2-way = free.
// Wave tile: 32M x 64N (acc[2][4]). IMGS=2 for conv4 (pool fused).
template<int CIN, int COUT, int HIN, int IMGS, bool POOL>
__global__ __launch_bounds__(256, 2)
void conv_mfma_kernel(const bf16* __restrict__ in, const bf16* __restrict__ wt,
                      const float* __restrict__ bias, bf16* __restrict__ out,
                      float* __restrict__ pooled, int img0) {
    constexpr int HOUT = HIN / 2;
    constexpr int PPI  = HOUT * HOUT;
    constexpr int K    = 9 * CIN;
    constexpr int S    = (K + 63) / 64;
    __shared__ short As[2][128][72];
    __shared__ short Bs[2][64][72];
    __shared__ float partial[4][64];

    int tid  = threadIdx.x;
    int lane = tid & 63;
    int wv   = tid >> 6;
    int bx   = blockIdx.x;
    int nblk = blockIdx.y;
    int bz   = blockIdx.z;

    // A staging: thread -> row ar (0..127), slot group asb (0 or 4)
    int ar  = tid & 127;
    int asb = (tid >> 7) * 4;
    int img_l, pos;
    if (IMGS > 1) { img_l = bz * IMGS + (ar / PPI); pos = ar % PPI; }
    else          { img_l = bz; pos = bx * 128 + ar; }
    int oy = pos / HOUT, ox = pos % HOUT;
    // B staging: thread -> row bn (0..63), slots bsb..bsb+1
    int bn = tid & 63, bsb = (tid >> 6) * 2;

    auto loadA = [&](int s, uint4* v) {
        int koff = s*64 + asb*8;          // uniform tap per thread-group of 4 slots
        int tap = koff / CIN, ic = koff % CIN;
        int ky = tap / 3, kx = tap % 3;
        int iy = 2*oy + ky, ix = 2*ox + kx;
        v[0] = v[1] = v[2] = v[3] = uint4{0u,0u,0u,0u};
        if (koff < K && iy < HIN && ix < HIN) {
            const bf16* p = in + (((size_t)img_l * HIN + iy) * HIN + ix) * CIN + ic;
            #pragma unroll
            for (int j = 0; j < 4; ++j) v[j] = *(const uint4*)(p + j*8);
        }
    };
    auto writeA = [&](const uint4* v, int buf) {
        #pragma unroll
        for (int j = 0; j < 4; ++j) *(uint4*)&As[buf][ar][(asb + j)*8] = v[j];
    };
    auto loadB = [&](int s, uint4* v) {
        #pragma unroll
        for (int j2 = 0; j2 < 2; ++j2) {
            int j = bsb + j2;
            int koff = s*64 + j*8;
            v[j2] = uint4{0u,0u,0u,0u};
            if (koff < K) {
                int tap = koff / CIN, ic = koff % CIN;
                v[j2] = *(const uint4*)(wt + ((size_t)tap * COUT + nblk*64 + bn) * CIN + ic);
            }
        }
    };
    auto writeB = [&](const uint4* v, int buf) {
        #pragma unroll
        for (int j2 = 0; j2 < 2; ++j2) *(uint4*)&Bs[buf][bn][(bsb + j2)*8] = v[j2];
    };

    f32x4 acc[2][4];
    #pragma unroll
    for (int i = 0; i < 2; ++i)
        #pragma unroll
        for (int j = 0; j < 4; ++j) acc[i][j] = f32x4{0.f, 0.f, 0.f, 0.f};

    {   // prologue: stage 0
        uint4 va[4], vb[2];
        loadA(0, va); loadB(0, vb);
        writeA(va, 0); writeB(vb, 0);
    }
    __syncthreads();

    for (int s = 0; s < S; ++s) {
        int cur = s & 1;
        uint4 va[4], vb[2];
        bool nxt = (s + 1 < S);
        if (nxt) { loadA(s + 1, va); loadB(s + 1, vb); }   // global loads in flight
        #pragma unroll
        for (int ks = 0; ks < 2; ++ks) {
            bf16x8 af[2], bfr[4];
            #pragma unroll
            for (int mi = 0; mi < 2; ++mi)
                af[mi] = *(const bf16x8*)&As[cur][wv*32 + mi*16 + (lane&15)][(ks*4 + (lane>>4))*8];
            #pragma unroll
            for (int ni = 0; ni < 4; ++ni)
                bfr[ni] = *(const bf16x8*)&Bs[cur][ni*16 + (lane&15)][(ks*4 + (lane>>4))*8];
            #pragma unroll
            for (int mi = 0; mi < 2; ++mi)
                #pragma unroll
                for (int ni = 0; ni < 4; ++ni)
                    acc[mi][ni] = __builtin_amdgcn_mfma_f32_16x16x32_bf16(af[mi], bfr[ni], acc[mi][ni], 0, 0, 0);
        }
        if (nxt) { writeA(va, cur ^ 1); writeB(vb, cur ^ 1); }
        __syncthreads();
    }

    // Epilogue. C/D layout: col = lane&15 (N), row = (lane>>4)*4 + rg (M).
    if (!POOL) {
        #pragma unroll
        for (int ni = 0; ni < 4; ++ni) {
            int oc = nblk*64 + ni*16 + (lane & 15);
            float b = bias[oc];
            #pragma unroll
            for (int mi = 0; mi < 2; ++mi) {
                #pragma unroll
                for (int rg = 0; rg < 4; ++rg) {
                    int rr = wv*32 + mi*16 + (lane>>4)*4 + rg;
                    int img_e, pos_e;
                    if (IMGS > 1) { img_e = bz*IMGS + rr/PPI; pos_e = rr % PPI; }
                    else          { img_e = bz; pos_e = bx*128 + rr; }
                    int oye = pos_e / HOUT, oxe = pos_e % HOUT;
                    float v = fmaxf(acc[mi][ni][rg] + b, 0.0f);
                    out[(((size_t)img_e * HOUT + oye) * HOUT + oxe) * COUT + oc] = __float2bfloat16(v);
                }
            }
        }
    } else {
        // wave w covers rows [32w, 32w+32) = half of image bz*IMGS + (w>>1)
        #pragma unroll
        for (int ni = 0; ni < 4; ++ni) {
            int oc = nblk*64 + ni*16 + (lane & 15);
            float b = bias[oc];
            float s = 0.0f;
            #pragma unroll
            for (int mi = 0; mi < 2; ++mi)
                #pragma unroll
                for (int rg = 0; rg < 4; ++rg) s += fmaxf(acc[mi][ni][rg] + b, 0.0f);
            s += __shfl_xor(s, 16);
            s += __shfl_xor(s, 32);
            if (lane < 16) partial[wv][ni*16 + lane] = s;
        }
        __syncthreads();
        if (tid < 64 * IMGS) {
            int e = tid >> 6, c = tid & 63;
            float v = partial[2*e][c] + partial[2*e + 1][c];
            pooled[((size_t)(img0 + bz*IMGS + e)) * 256 + nblk*64 + c] = v * (1.0f/64.0f);
        }
    }
}

// ---- FC 256->128 per image ----
__global__ void fc_kernel(const float* __restrict__ pooled, const float* __restrict__ Wfc,
                          const float* __restrict__ bfc, float* __restrict__ z) {
    int n = blockIdx.x;    // 512
    int t = threadIdx.x;   // 128
    const float* hp = pooled + (size_t)n * 256;
    float acc = bfc[t];
    for (int k = 0; k < 256; ++k) acc = fmaf(hp[k], Wfc[(size_t)k*kLatent + t], acc);
    z[(size_t)n*kLatent + t] = acc;
}

// ---- mean over the 32 channel-images ----
__global__ void final_mean_kernel(const float* __restrict__ z, float* __restrict__ out) {
    int b = blockIdx.x;    // 16
    int l = threadIdx.x;   // 128
    float s = 0.0f;
    #pragma unroll
    for (int c = 0; c < kC; ++c) s += z[((size_t)(b*kC + c))*kLatent + l];
    out[(size_t)b*kLatent + l] = s * (1.0f/kC);
}

extern "C" void kernel_launch(void* const* d_in, const int* in_sizes, int n_in,
                              void* d_out, int out_size, void* d_ws, size_t ws_size,
                              hipStream_t stream) {
    const float* x_raw = (const float*)d_in[0];
    const float* W1 = (const float*)d_in[1];  const float* b1 = (const float*)d_in[2];
    const float* W2 = (const float*)d_in[3];  const float* b2 = (const float*)d_in[4];
    const float* W3 = (const float*)d_in[5];  const float* b3 = (const float*)d_in[6];
    const float* W4 = (const float*)d_in[7];  const float* b4 = (const float*)d_in[8];
    const float* Wfc = (const float*)d_in[9]; const float* bfc = (const float*)d_in[10];
    float* out = (float*)d_out;

    char* wsb = (char*)d_ws;
    float* xn     = (float*)(wsb);                      // 256 KiB
    float* sq     = (float*)(wsb + (256u<<10));         // 256 KiB
    float* z      = (float*)(wsb + (512u<<10));         // 256 KiB
    float* pooled = (float*)(wsb + (768u<<10));         // 512 KiB
    bf16* Wt2     = (bf16*)(wsb + (1280u<<10));         // 36 KiB
    bf16* Wt3     = (bf16*)(wsb + (1316u<<10));         // 144 KiB
    bf16* Wt4     = (bf16*)(wsb + (1460u<<10));         // 576 KiB
    char* chunk_base = wsb + (2048u<<10);               // 2 MiB header

    const size_t perH1 = 64u*64u*32u*2u, perH2 = 32u*32u*64u*2u, perH3 = 16u*16u*128u*2u;
    const size_t perImg = perH1 + perH2 + perH3;
    int chunk = 4;
    for (int c = 512; c >= 4; c >>= 1) {
        if ((2048u<<10) + (size_t)c * perImg <= ws_size) { chunk = c; break; }
    }

    gaf_stats_kernel<<<kBC, kS, 0, stream>>>(x_raw, xn, sq);
    wtrans_kernel<<<(9*64*32 + 255)/256, 256, 0, stream>>>(W2, Wt2, 64, 32);
    wtrans_kernel<<<(9*128*64 + 255)/256, 256, 0, stream>>>(W3, Wt3, 128, 64);
    wtrans_kernel<<<(9*256*128 + 255)/256, 256, 0, stream>>>(W4, Wt4, 256, 128);

    for (int img0 = 0; img0 < kBC; img0 += chunk) {
        int nimg = chunk;
        bf16* h1 = (bf16*)chunk_base;
        bf16* h2 = (bf16*)(chunk_base + (size_t)chunk * perH1);
        bf16* h3 = (bf16*)(chunk_base + (size_t)chunk * (perH1 + perH2));

        // conv1: 2->32, 128->64
        conv1_gaf_kernel<<<dim3(16, nimg), 256, 0, stream>>>(xn, sq, W1, b1, h1, img0);
        // conv2: 32->64, 64->32 : M=1024/img -> 8 mblk x 128, N=64
        conv_mfma_kernel<32, 64, 64, 1, false>
            <<<dim3(8, 1, nimg), 256, 0, stream>>>(h1, Wt2, b2, h2, nullptr, img0);
        // conv3: 64->128, 32->16 : M=256/img -> 2 mblk, N=128 -> 2 nblk
        conv_mfma_kernel<64, 128, 32, 1, false>
            <<<dim3(2, 2, nimg), 256, 0, stream>>>(h2, Wt3, b3, h3, nullptr, img0);
        // conv4: 128->256, 16->8 : 2 imgs/block (M=128), N=256 -> 4 nblk, fused pool
        conv_mfma_kernel<128, 256, 16, 2, true>
            <<<dim3(1, 4, nimg/2), 256, 0, stream>>>(h3, Wt4, b4, nullptr, pooled, img0);
    }

    fc_kernel<<<kBC, kLatent, 0, stream>>>(pooled, Wfc, bfc, z);
    final_mean_kernel<<<kB, kLatent, 0, stream>>>(z, out);
}

// Round 6
// 303.306 us; speedup vs baseline: 46.3837x; 1.0705x over previous
//
#include <hip/hip_runtime.h>
#include <hip/hip_bf16.h>

#define DEV __device__ __forceinline__

constexpr int kB = 16, kC = 32, kT = 512, kS = 128, kBC = 512, kLatent = 128;
constexpr float kEps = 1e-8f;

using bf16 = __hip_bfloat16;
using bf16x8 = __attribute__((ext_vector_type(8))) short;   // 8 bf16 = 4 VGPRs
using f32x4  = __attribute__((ext_vector_type(4))) float;

DEV unsigned short f2bf(float v) {
    bf16 h = __float2bfloat16(v);
    return *(unsigned short*)&h;
}

// ---- per-(b,c) downsample + min/max normalize + sqrt term ----
__global__ void gaf_stats_kernel(const float* __restrict__ x_raw,
                                 float* __restrict__ xn, float* __restrict__ sq) {
    int bc = blockIdx.x;       // 512
    int s  = threadIdx.x;      // 128
    const float* xp = x_raw + (size_t)bc * kT;
    float v = 0.25f * (xp[4*s] + xp[4*s+1] + xp[4*s+2] + xp[4*s+3]);
    __shared__ float smn[kS], smx[kS];
    smn[s] = v; smx[s] = v;
    __syncthreads();
    for (int off = kS/2; off > 0; off >>= 1) {
        if (s < off) {
            smn[s] = fminf(smn[s], smn[s+off]);
            smx[s] = fmaxf(smx[s], smx[s+off]);
        }
        __syncthreads();
    }
    float mn = smn[0], mx = smx[0];
    float xv = 2.0f * (v - mn) / (mx - mn + kEps) - 1.0f;
    xv = fminf(fmaxf(xv, -1.0f), 1.0f);
    float sv = sqrtf(fminf(fmaxf(1.0f - xv*xv, 0.0f), 1.0f));
    xn[bc*kS + s] = xv;
    sq[bc*kS + s] = sv;
}

// ---- weight transpose: OIHW f32 -> [tap][oc][ic] bf16 ----
__global__ void wtrans_kernel(const float* __restrict__ w, bf16* __restrict__ wt,
                              int COUT, int CIN) {
    int total = 9 * COUT * CIN;
    int idx = blockIdx.x * blockDim.x + threadIdx.x;
    if (idx >= total) return;
    int ic = idx % CIN;
    int oc = (idx / CIN) % COUT;
    int t  = idx / (CIN * COUT);
    wt[((size_t)t * COUT + oc) * CIN + ic] = __float2bfloat16(w[((size_t)oc * CIN + ic) * 9 + t]);
}

// ---- FUSED conv1+conv2 ----
// Block = one image x 4 conv2-output rows (M=128, N=64 = all oc2).
// Phase 1: compute the 9-row h1 halo tile (scalar conv1, all 32 oc/thread)
//          into LDS (bf16, row stride 80 B -> odd 16B-group stride, conflict-free).
// Phase 2: conv2 GEMM; A read directly from the h1 tile (no staging, no A
//          global traffic); B (one tap = 4 KiB) double-buffered, 1 barrier/tap.
__global__ __launch_bounds__(256, 2)
void conv12_kernel(const float* __restrict__ xn, const float* __restrict__ sq,
                   const float* __restrict__ w1, const float* __restrict__ b1,
                   const bf16* __restrict__ wt2, const float* __restrict__ b2,
                   bf16* __restrict__ out, int img0) {
    __shared__ float xl[kS], sl[kS];
    __shared__ short h1t[576][40];   // 9 rows x 64 x (32 oc + pad to 40)
    __shared__ short Bs[2][64][40];

    int tid  = threadIdx.x;
    int lane = tid & 63;
    int wv   = tid >> 6;
    int mblk = blockIdx.x;   // 0..7 -> conv2 rows 4*mblk..4*mblk+3
    int bz   = blockIdx.y;   // chunk-local image
    int bc   = img0 + bz;

    if (tid < 128) xl[tid] = xn[(size_t)bc * kS + tid];
    else           sl[tid - 128] = sq[(size_t)bc * kS + (tid - 128)];
    __syncthreads();

    // ---- Phase 1: h1 tile rows iy = 8*mblk .. 8*mblk+8 ----
    for (int it = 0; it < 3; ++it) {
        int idx = it * 256 + tid;
        if (idx < 576) {
            int trow = idx >> 6, hx = idx & 63;
            int iy = 8 * mblk + trow;
            unsigned int pk[16];
            if (iy < 64) {
                float xr[3], sr[3], xc[3], sc[3];
                #pragma unroll
                for (int k = 0; k < 3; ++k) {
                    int iyy = 2*iy + k, ixx = 2*hx + k;
                    bool vy = iyy < kS, vx = ixx < kS;
                    xr[k] = vy ? xl[iyy] : 0.0f;  sr[k] = vy ? sl[iyy] : 0.0f;
                    xc[k] = vx ? xl[ixx] : 0.0f;  sc[k] = vx ? sl[ixx] : 0.0f;
                }
                float g0[9], g1[9];
                #pragma unroll
                for (int ky = 0; ky < 3; ++ky)
                    #pragma unroll
                    for (int kx = 0; kx < 3; ++kx) {
                        g0[ky*3+kx] = xr[ky]*xc[kx] - sr[ky]*sc[kx];
                        g1[ky*3+kx] = sr[ky]*xc[kx] - xr[ky]*sc[kx];
                    }
                #pragma unroll
                for (int oc = 0; oc < 32; ++oc) {
                    const float* wr = w1 + oc*18;   // uniform -> s_load
                    float acc = b1[oc];
                    #pragma unroll
                    for (int t = 0; t < 9; ++t) {
                        acc = fmaf(g0[t], wr[t],   acc);
                        acc = fmaf(g1[t], wr[9+t], acc);
                    }
                    unsigned int b = f2bf(fmaxf(acc, 0.0f));
                    if (oc & 1) pk[oc >> 1] |= b << 16;
                    else        pk[oc >> 1]  = b;
                }
            } else {
                #pragma unroll
                for (int j = 0; j < 16; ++j) pk[j] = 0u;   // SAME padding row
            }
            #pragma unroll
            for (int j = 0; j < 4; ++j) *(uint4*)&h1t[idx][j*8] = ((uint4*)pk)[j];
        }
    }

    // ---- Phase 2: conv2 GEMM, K = 9 taps x 32 ic ----
    int brow = tid >> 2, bseg = tid & 3;
    uint4 vb = *(const uint4*)(wt2 + ((size_t)0*64 + brow)*32 + bseg*8);
    *(uint4*)&Bs[0][brow][bseg*8] = vb;
    __syncthreads();

    f32x4 acc[2][4];
    #pragma unroll
    for (int i = 0; i < 2; ++i)
        #pragma unroll
        for (int j = 0; j < 4; ++j) acc[i][j] = f32x4{0.f, 0.f, 0.f, 0.f};

    for (int tap = 0; tap < 9; ++tap) {
        int cur = tap & 1;
        bool nxt = tap < 8;
        uint4 vb2;
        if (nxt) vb2 = *(const uint4*)(wt2 + ((size_t)(tap+1)*64 + brow)*32 + bseg*8);
        int ky = tap / 3, kx = tap % 3;
        bf16x8 af[2], bfr[4];
        int trow = 2*wv + ky;
        #pragma unroll
        for (int mi = 0; mi < 2; ++mi) {
            int ocol = mi*16 + (lane & 15);
            int x = 2*ocol + kx;
            bf16x8 z = {0,0,0,0,0,0,0,0};
            af[mi] = (x < 64) ? *(const bf16x8*)&h1t[trow*64 + x][(lane>>4)*8] : z;
        }
        #pragma unroll
        for (int ni = 0; ni < 4; ++ni)
            bfr[ni] = *(const bf16x8*)&Bs[cur][ni*16 + (lane&15)][(lane>>4)*8];
        #pragma unroll
        for (int mi = 0; mi < 2; ++mi)
            #pragma unroll
            for (int ni = 0; ni < 4; ++ni)
                acc[mi][ni] = __builtin_amdgcn_mfma_f32_16x16x32_bf16(af[mi], bfr[ni], acc[mi][ni], 0, 0, 0);
        if (nxt) *(uint4*)&Bs[cur ^ 1][brow][bseg*8] = vb2;
        __syncthreads();
    }

    // ---- epilogue: h2 NHWC [bz][32][32][64] ----
    int oy = 4*mblk + wv;
    #pragma unroll
    for (int ni = 0; ni < 4; ++ni) {
        int oc = ni*16 + (lane & 15);
        float b = b2[oc];
        #pragma unroll
        for (int mi = 0; mi < 2; ++mi)
            #pragma unroll
            for (int rg = 0; rg < 4; ++rg) {
                int ocol = 16*mi + (lane>>4)*4 + rg;
                float v = fmaxf(acc[mi][ni][rg] + b, 0.0f);
                out[(((size_t)bz*32 + oy)*32 + ocol)*64 + oc] = __float2bfloat16(v);
            }
    }
}

// ---- MFMA implicit-GEMM conv (conv3/conv4), BK=32 double-buffered ----
// Block 128M x 64N, 4 waves (wave 32Mx64N), 1 barrier/stage, 8 MFMA/wave/stage.
// Row stride 40 shorts = 80 B (odd 16B-group stride) -> conflict-free b128.
template<int CIN, int COUT, int HIN, int IMGS, bool POOL>
__global__ __launch_bounds__(256, 4)
void conv_mfma_kernel(const bf16* __restrict__ in, const bf16* __restrict__ wt,
                      const float* __restrict__ bias, bf16* __restrict__ out,
                      float* __restrict__ pooled, int img0) {
    constexpr int HOUT = HIN / 2;
    constexpr int PPI  = HOUT * HOUT;
    constexpr int K    = 9 * CIN;
    constexpr int S    = K / 32;
    __shared__ short As[2][128][40];
    __shared__ short Bs[2][64][40];
    __shared__ float partial[4][64];

    int tid  = threadIdx.x;
    int lane = tid & 63;
    int wv   = tid >> 6;
    int bx   = blockIdx.x;
    int nblk = blockIdx.y;
    int bz   = blockIdx.z;

    int ar = tid & 127, ah = tid >> 7;       // A: row ar, k-half ah (16 k each)
    int img_l, pos;
    if (IMGS > 1) { img_l = bz * IMGS + (ar / PPI); pos = ar % PPI; }
    else          { img_l = bz; pos = bx * 128 + ar; }
    int oy = pos / HOUT, ox = pos % HOUT;
    int brow = tid & 63, bslot = tid >> 6;   // B: row brow, 8-k slot bslot

    auto loadA = [&](int s, uint4* v) {
        int k0 = s*32 + ah*16;
        int tap = k0 / CIN, ic = k0 % CIN;
        int ky = tap / 3, kx = tap % 3;
        int iy = 2*oy + ky, ix = 2*ox + kx;
        v[0] = uint4{0u,0u,0u,0u}; v[1] = uint4{0u,0u,0u,0u};
        if (iy < HIN && ix < HIN) {
            const bf16* p = in + (((size_t)img_l * HIN + iy) * HIN + ix) * CIN + ic;
            v[0] = *(const uint4*)p;
            v[1] = *(const uint4*)(p + 8);
        }
    };
    auto writeA = [&](const uint4* v, int buf) {
        *(uint4*)&As[buf][ar][(2*ah)*8]   = v[0];
        *(uint4*)&As[buf][ar][(2*ah+1)*8] = v[1];
    };
    auto loadB = [&](int s, uint4& v) {
        int k = s*32 + bslot*8;
        int tap = k / CIN, ic = k % CIN;
        v = *(const uint4*)(wt + ((size_t)tap * COUT + nblk*64 + brow) * CIN + ic);
    };
    auto writeB = [&](uint4 v, int buf) {
        *(uint4*)&Bs[buf][brow][bslot*8] = v;
    };

    f32x4 acc[2][4];
    #pragma unroll
    for (int i = 0; i < 2; ++i)
        #pragma unroll
        for (int j = 0; j < 4; ++j) acc[i][j] = f32x4{0.f, 0.f, 0.f, 0.f};

    {   // prologue
        uint4 va[2]; uint4 vb;
        loadA(0, va); loadB(0, vb);
        writeA(va, 0); writeB(vb, 0);
    }
    __syncthreads();

    for (int s = 0; s < S; ++s) {
        int cur = s & 1;
        bool nxt = (s + 1 < S);
        uint4 va[2]; uint4 vb;
        if (nxt) { loadA(s + 1, va); loadB(s + 1, vb); }
        bf16x8 af[2], bfr[4];
        #pragma unroll
        for (int mi = 0; mi < 2; ++mi)
            af[mi] = *(const bf16x8*)&As[cur][wv*32 + mi*16 + (lane&15)][(lane>>4)*8];
        #pragma unroll
        for (int ni = 0; ni < 4; ++ni)
            bfr[ni] = *(const bf16x8*)&Bs[cur][ni*16 + (lane&15)][(lane>>4)*8];
        #pragma unroll
        for (int mi = 0; mi < 2; ++mi)
            #pragma unroll
            for (int ni = 0; ni < 4; ++ni)
                acc[mi][ni] = __builtin_amdgcn_mfma_f32_16x16x32_bf16(af[mi], bfr[ni], acc[mi][ni], 0, 0, 0);
        if (nxt) { writeA(va, cur ^ 1); writeB(vb, cur ^ 1); }
        __syncthreads();
    }

    if (!POOL) {
        #pragma unroll
        for (int ni = 0; ni < 4; ++ni) {
            int oc = nblk*64 + ni*16 + (lane & 15);
            float b = bias[oc];
            #pragma unroll
            for (int mi = 0; mi < 2; ++mi)
                #pragma unroll
                for (int rg = 0; rg < 4; ++rg) {
                    int rr = wv*32 + mi*16 + (lane>>4)*4 + rg;
                    int img_e, pos_e;
                    if (IMGS > 1) { img_e = bz*IMGS + rr/PPI; pos_e = rr % PPI; }
                    else          { img_e = bz; pos_e = bx*128 + rr; }
                    int oye = pos_e / HOUT, oxe = pos_e % HOUT;
                    float v = fmaxf(acc[mi][ni][rg] + b, 0.0f);
                    out[(((size_t)img_e * HOUT + oye) * HOUT + oxe) * COUT + oc] = __float2bfloat16(v);
                }
        }
    } else {
        #pragma unroll
        for (int ni = 0; ni < 4; ++ni) {
            int oc = nblk*64 + ni*16 + (lane & 15);
            float b = bias[oc];
            float s = 0.0f;
            #pragma unroll
            for (int mi = 0; mi < 2; ++mi)
                #pragma unroll
                for (int rg = 0; rg < 4; ++rg) s += fmaxf(acc[mi][ni][rg] + b, 0.0f);
            s += __shfl_xor(s, 16);
            s += __shfl_xor(s, 32);
            if (lane < 16) partial[wv][ni*16 + lane] = s;
        }
        __syncthreads();
        if (tid < 64 * IMGS) {
            int e = tid >> 6, c = tid & 63;
            float v = partial[2*e][c] + partial[2*e + 1][c];
            pooled[((size_t)(img0 + bz*IMGS + e)) * 256 + nblk*64 + c] = v * (1.0f/64.0f);
        }
    }
}

// ---- FC 256->128 per image ----
__global__ void fc_kernel(const float* __restrict__ pooled, const float* __restrict__ Wfc,
                          const float* __restrict__ bfc, float* __restrict__ z) {
    int n = blockIdx.x;    // 512
    int t = threadIdx.x;   // 128
    const float* hp = pooled + (size_t)n * 256;
    float acc = bfc[t];
    for (int k = 0; k < 256; ++k) acc = fmaf(hp[k], Wfc[(size_t)k*kLatent + t], acc);
    z[(size_t)n*kLatent + t] = acc;
}

// ---- mean over the 32 channel-images ----
__global__ void final_mean_kernel(const float* __restrict__ z, float* __restrict__ out) {
    int b = blockIdx.x;    // 16
    int l = threadIdx.x;   // 128
    float s = 0.0f;
    #pragma unroll
    for (int c = 0; c < kC; ++c) s += z[((size_t)(b*kC + c))*kLatent + l];
    out[(size_t)b*kLatent + l] = s * (1.0f/kC);
}

extern "C" void kernel_launch(void* const* d_in, const int* in_sizes, int n_in,
                              void* d_out, int out_size, void* d_ws, size_t ws_size,
                              hipStream_t stream) {
    const float* x_raw = (const float*)d_in[0];
    const float* W1 = (const float*)d_in[1];  const float* b1 = (const float*)d_in[2];
    const float* W2 = (const float*)d_in[3];  const float* b2 = (const float*)d_in[4];
    const float* W3 = (const float*)d_in[5];  const float* b3 = (const float*)d_in[6];
    const float* W4 = (const float*)d_in[7];  const float* b4 = (const float*)d_in[8];
    const float* Wfc = (const float*)d_in[9]; const float* bfc = (const float*)d_in[10];
    float* out = (float*)d_out;

    char* wsb = (char*)d_ws;
    float* xn     = (float*)(wsb);                      // 256 KiB
    float* sq     = (float*)(wsb + (256u<<10));         // 256 KiB
    float* z      = (float*)(wsb + (512u<<10));         // 256 KiB
    float* pooled = (float*)(wsb + (768u<<10));         // 512 KiB
    bf16* Wt2     = (bf16*)(wsb + (1280u<<10));         // 36 KiB
    bf16* Wt3     = (bf16*)(wsb + (1316u<<10));         // 144 KiB
    bf16* Wt4     = (bf16*)(wsb + (1460u<<10));         // 576 KiB
    char* chunk_base = wsb + (2048u<<10);               // 2 MiB header

    // Per-image: h2 NHWC bf16 128 KiB + h3 64 KiB (h1 never materialized)
    const size_t perH2 = 32u*32u*64u*2u, perH3 = 16u*16u*128u*2u;
    const size_t perImg = perH2 + perH3;
    int chunk = 4;
    for (int c = 512; c >= 4; c >>= 1) {
        if ((2048u<<10) + (size_t)c * perImg <= ws_size) { chunk = c; break; }
    }

    gaf_stats_kernel<<<kBC, kS, 0, stream>>>(x_raw, xn, sq);
    wtrans_kernel<<<(9*64*32 + 255)/256, 256, 0, stream>>>(W2, Wt2, 64, 32);
    wtrans_kernel<<<(9*128*64 + 255)/256, 256, 0, stream>>>(W3, Wt3, 128, 64);
    wtrans_kernel<<<(9*256*128 + 255)/256, 256, 0, stream>>>(W4, Wt4, 256, 128);

    for (int img0 = 0; img0 < kBC; img0 += chunk) {
        int nimg = chunk;
        bf16* h2 = (bf16*)chunk_base;
        bf16* h3 = (bf16*)(chunk_base + (size_t)chunk * perH2);

        // fused conv1+conv2: 2->32->64, 128->64->32
        conv12_kernel<<<dim3(8, nimg), 256, 0, stream>>>(xn, sq, W1, b1, Wt2, b2, h2, img0);
        // conv3: 64->128, 32->16 : M=256/img -> 2 mblk, N=128 -> 2 nblk
        conv_mfma_kernel<64, 128, 32, 1, false>
            <<<dim3(2, 2, nimg), 256, 0, stream>>>(h2, Wt3, b3, h3, nullptr, img0);
        // conv4: 128->256, 16->8 : 2 imgs/block (M=128), N=256 -> 4 nblk, fused pool
        conv_mfma_kernel<128, 256, 16, 2, true>
            <<<dim3(1, 4, nimg/2), 256, 0, stream>>>(h3, Wt4, b4, nullptr, pooled, img0);
    }

    fc_kernel<<<kBC, kLatent, 0, stream>>>(pooled, Wfc, bfc, z);
    final_mean_kernel<<<kB, kLatent, 0, stream>>>(z, out);
}

// Round 7
// 277.556 us; speedup vs baseline: 50.6868x; 1.0928x over previous
//
#include <hip/hip_runtime.h>
#include <hip/hip_bf16.h>

#define DEV __device__ __forceinline__

constexpr int kB = 16, kC = 32, kT = 512, kS = 128, kBC = 512, kLatent = 128;
constexpr float kEps = 1e-8f;

using bf16 = __hip_bfloat16;
using bf16x8 = __attribute__((ext_vector_type(8))) short;   // 8 bf16 = 4 VGPRs
using f32x4  = __attribute__((ext_vector_type(4))) float;

DEV unsigned short f2bf(float v) {
    bf16 h = __float2bfloat16(v);
    return *(unsigned short*)&h;
}

// ---- per-(b,c) downsample + min/max normalize + sqrt term ----
__global__ void gaf_stats_kernel(const float* __restrict__ x_raw,
                                 float* __restrict__ xn, float* __restrict__ sq) {
    int bc = blockIdx.x;       // 512
    int s  = threadIdx.x;      // 128
    const float* xp = x_raw + (size_t)bc * kT;
    float v = 0.25f * (xp[4*s] + xp[4*s+1] + xp[4*s+2] + xp[4*s+3]);
    __shared__ float smn[kS], smx[kS];
    smn[s] = v; smx[s] = v;
    __syncthreads();
    for (int off = kS/2; off > 0; off >>= 1) {
        if (s < off) {
            smn[s] = fminf(smn[s], smn[s+off]);
            smx[s] = fmaxf(smx[s], smx[s+off]);
        }
        __syncthreads();
    }
    float mn = smn[0], mx = smx[0];
    float xv = 2.0f * (v - mn) / (mx - mn + kEps) - 1.0f;
    xv = fminf(fmaxf(xv, -1.0f), 1.0f);
    float sv = sqrtf(fminf(fmaxf(1.0f - xv*xv, 0.0f), 1.0f));
    xn[bc*kS + s] = xv;
    sq[bc*kS + s] = sv;
}

// ---- weight transpose: OIHW f32 -> [tap][oc][ic] bf16 ----
__global__ void wtrans_kernel(const float* __restrict__ w, bf16* __restrict__ wt,
                              int COUT, int CIN) {
    int total = 9 * COUT * CIN;
    int idx = blockIdx.x * blockDim.x + threadIdx.x;
    if (idx >= total) return;
    int ic = idx % CIN;
    int oc = (idx / CIN) % COUT;
    int t  = idx / (CIN * COUT);
    wt[((size_t)t * COUT + oc) * CIN + ic] = __float2bfloat16(w[((size_t)oc * CIN + ic) * 9 + t]);
}

// ---- conv1 weight pack: [oc][18] f32 -> [oc][32] bf16 (k<18 real, rest 0) ----
__global__ void wtrans1_kernel(const float* __restrict__ w1, bf16* __restrict__ w1b) {
    int idx = blockIdx.x * blockDim.x + threadIdx.x;   // 1024
    if (idx >= 32 * 32) return;
    int oc = idx >> 5, k = idx & 31;
    float v = (k < 18) ? w1[oc * 18 + k] : 0.0f;
    w1b[idx] = __float2bfloat16(v);
}

// ---- FUSED conv1+conv2 ----
// Phase 1a: per h1-position compute the 18 GAF-products G (fp32->bf16) into LDS.
// Phase 1b: h1 = relu(G[576x32] @ W1b^T[32x32] + b1) via MFMA; write h1 back
//           IN-PLACE over G (union) in a parity-split layout (even/odd x tiles)
//           so phase-2 A-reads are stride-1-row (80 B, odd quad) = conflict-free.
// Phase 2: conv2 GEMM (K = 9 taps x 32 ic); B double-buffered, 1 barrier/tap.
__global__ __launch_bounds__(256, 2)
void conv12_kernel(const float* __restrict__ xn, const float* __restrict__ sq,
                   const bf16* __restrict__ w1b, const float* __restrict__ b1,
                   const bf16* __restrict__ wt2, const float* __restrict__ b2,
                   bf16* __restrict__ out, int img0) {
    __shared__ float xl[kS], sl[kS];
    __shared__ union { short G[576][40]; short H[2][288][40]; } U;  // 46 KiB
    __shared__ short Bs[2][64][40];                                  // 10 KiB
    __shared__ short W1s[32][40];                                    // 2.5 KiB

    int tid  = threadIdx.x;
    int lane = tid & 63;
    int wv   = tid >> 6;
    int mblk = blockIdx.x;   // 0..7 -> conv2 rows 4*mblk..4*mblk+3
    int bz   = blockIdx.y;   // chunk-local image
    int bc   = img0 + bz;

    if (tid < 128) {
        xl[tid] = xn[(size_t)bc * kS + tid];
        int rr = tid >> 2, sg = tid & 3;
        *(uint4*)&W1s[rr][sg*8] = *(const uint4*)(w1b + rr*32 + sg*8);
    } else {
        sl[tid - 128] = sq[(size_t)bc * kS + (tid - 128)];
    }
    __syncthreads();

    // ---- Phase 1a: G rows for h1 tile rows iy = 8*mblk .. 8*mblk+8 ----
    #pragma unroll
    for (int it = 0; it < 3; ++it) {
        int idx = it * 256 + tid;
        if (idx >= 576) break;
        int trow = idx >> 6, hx = idx & 63;
        int iy = 8 * mblk + trow;
        unsigned int pk[16];
        #pragma unroll
        for (int j = 0; j < 16; ++j) pk[j] = 0u;
        if (iy < 64) {
            float xr[3], sr[3], xc[3], sc[3];
            #pragma unroll
            for (int k = 0; k < 3; ++k) {
                int iyy = 2*iy + k, ixx = 2*hx + k;
                bool vy = iyy < kS, vx = ixx < kS;
                xr[k] = vy ? xl[iyy] : 0.0f;  sr[k] = vy ? sl[iyy] : 0.0f;
                xc[k] = vx ? xl[ixx] : 0.0f;  sc[k] = vx ? sl[ixx] : 0.0f;
            }
            unsigned short gs[18];
            #pragma unroll
            for (int ky = 0; ky < 3; ++ky)
                #pragma unroll
                for (int kx = 0; kx < 3; ++kx) {
                    gs[ky*3+kx]   = f2bf(xr[ky]*xc[kx] - sr[ky]*sc[kx]);  // gasf
                    gs[9+ky*3+kx] = f2bf(sr[ky]*xc[kx] - xr[ky]*sc[kx]);  // gadf
                }
            #pragma unroll
            for (int j = 0; j < 9; ++j)
                pk[j] = (unsigned int)gs[2*j] | ((unsigned int)gs[2*j+1] << 16);
        }
        #pragma unroll
        for (int j = 0; j < 4; ++j) *(uint4*)&U.G[idx][j*8] = ((uint4*)pk)[j];
    }
    __syncthreads();

    // ---- Phase 1b: h1 = relu(G @ W1b^T + b1) via MFMA ----
    int brow = tid >> 2, bseg = tid & 3;
    uint4 vb0 = *(const uint4*)(wt2 + ((size_t)brow)*32 + bseg*8);   // conv2 tap 0

    f32x4 c1[9][2];
    bf16x8 w1f0 = *(const bf16x8*)&W1s[(lane & 15)][(lane>>4)*8];
    bf16x8 w1f1 = *(const bf16x8*)&W1s[16 + (lane & 15)][(lane>>4)*8];
    #pragma unroll
    for (int j = 0; j < 9; ++j) {
        int mt = 4*j + wv;   // 0..35
        bf16x8 af = *(const bf16x8*)&U.G[mt*16 + (lane & 15)][(lane>>4)*8];
        f32x4 zz = f32x4{0.f, 0.f, 0.f, 0.f};
        c1[j][0] = __builtin_amdgcn_mfma_f32_16x16x32_bf16(af, w1f0, zz, 0, 0, 0);
        c1[j][1] = __builtin_amdgcn_mfma_f32_16x16x32_bf16(af, w1f1, zz, 0, 0, 0);
    }
    __syncthreads();   // all G reads complete before overwrite

    #pragma unroll
    for (int j = 0; j < 9; ++j) {
        int mt = 4*j + wv;
        #pragma unroll
        for (int h = 0; h < 2; ++h) {
            int oc = h*16 + (lane & 15);
            float bb = b1[oc];
            #pragma unroll
            for (int rg = 0; rg < 4; ++rg) {
                int pos = mt*16 + (lane>>4)*4 + rg;
                int trow = pos >> 6, hx = pos & 63;
                float v = fmaxf(c1[j][h][rg] + bb, 0.0f);
                if (8*mblk + trow >= 64) v = 0.0f;   // SAME padding row
                U.H[hx & 1][trow*32 + (hx >> 1)][oc] = (short)f2bf(v);
            }
        }
    }
    *(uint4*)&Bs[0][brow][bseg*8] = vb0;
    __syncthreads();

    // ---- Phase 2: conv2 GEMM, K = 9 taps x 32 ic ----
    f32x4 acc[2][4];
    #pragma unroll
    for (int i = 0; i < 2; ++i)
        #pragma unroll
        for (int j = 0; j < 4; ++j) acc[i][j] = f32x4{0.f, 0.f, 0.f, 0.f};

    for (int tap = 0; tap < 9; ++tap) {
        int cur = tap & 1;
        bool nxt = tap < 8;
        uint4 vb2;
        if (nxt) vb2 = *(const uint4*)(wt2 + ((size_t)(tap+1)*64 + brow)*32 + bseg*8);
        int ky = tap / 3, kx = tap % 3;
        int trow = 2*wv + ky;
        bf16x8 af[2], bfr[4];
        #pragma unroll
        for (int mi = 0; mi < 2; ++mi) {
            int ocol = mi*16 + (lane & 15);
            int x = 2*ocol + kx;
            bf16x8 z = {0,0,0,0,0,0,0,0};
            af[mi] = (x < 64) ? *(const bf16x8*)&U.H[kx & 1][trow*32 + (x>>1)][(lane>>4)*8] : z;
        }
        #pragma unroll
        for (int ni = 0; ni < 4; ++ni)
            bfr[ni] = *(const bf16x8*)&Bs[cur][ni*16 + (lane&15)][(lane>>4)*8];
        #pragma unroll
        for (int mi = 0; mi < 2; ++mi)
            #pragma unroll
            for (int ni = 0; ni < 4; ++ni)
                acc[mi][ni] = __builtin_amdgcn_mfma_f32_16x16x32_bf16(af[mi], bfr[ni], acc[mi][ni], 0, 0, 0);
        if (nxt) *(uint4*)&Bs[cur ^ 1][brow][bseg*8] = vb2;
        __syncthreads();
    }

    // ---- epilogue: h2 NHWC [bz][32][32][64] ----
    int oy = 4*mblk + wv;
    #pragma unroll
    for (int ni = 0; ni < 4; ++ni) {
        int oc = ni*16 + (lane & 15);
        float b = b2[oc];
        #pragma unroll
        for (int mi = 0; mi < 2; ++mi)
            #pragma unroll
            for (int rg = 0; rg < 4; ++rg) {
                int ocol = 16*mi + (lane>>4)*4 + rg;
                float v = fmaxf(acc[mi][ni][rg] + b, 0.0f);
                out[(((size_t)bz*32 + oy)*32 + ocol)*64 + oc] = __float2bfloat16(v);
            }
    }
}

// ---- MFMA implicit-GEMM conv (conv3/conv4), BK=32 double-buffered ----
// Block 128M x 64N, 4 waves (wave 32Mx64N), 1 barrier/stage, 8 MFMA/wave/stage.
// Row stride 40 shorts = 80 B (odd 16B-group stride) -> conflict-free b128.
template<int CIN, int COUT, int HIN, int IMGS, bool POOL>
__global__ __launch_bounds__(256, 4)
void conv_mfma_kernel(const bf16* __restrict__ in, const bf16* __restrict__ wt,
                      const float* __restrict__ bias, bf16* __restrict__ out,
                      float* __restrict__ pooled, int img0) {
    constexpr int HOUT = HIN / 2;
    constexpr int PPI  = HOUT * HOUT;
    constexpr int K    = 9 * CIN;
    constexpr int S    = K / 32;
    __shared__ short As[2][128][40];
    __shared__ short Bs[2][64][40];
    __shared__ float partial[4][64];

    int tid  = threadIdx.x;
    int lane = tid & 63;
    int wv   = tid >> 6;
    int bx   = blockIdx.x;
    int nblk = blockIdx.y;
    int bz   = blockIdx.z;

    int ar = tid & 127, ah = tid >> 7;       // A: row ar, k-half ah (16 k each)
    int img_l, pos;
    if (IMGS > 1) { img_l = bz * IMGS + (ar / PPI); pos = ar % PPI; }
    else          { img_l = bz; pos = bx * 128 + ar; }
    int oy = pos / HOUT, ox = pos % HOUT;
    int brow = tid & 63, bslot = tid >> 6;   // B: row brow, 8-k slot bslot

    auto loadA = [&](int s, uint4* v) {
        int k0 = s*32 + ah*16;
        int tap = k0 / CIN, ic = k0 % CIN;
        int ky = tap / 3, kx = tap % 3;
        int iy = 2*oy + ky, ix = 2*ox + kx;
        v[0] = uint4{0u,0u,0u,0u}; v[1] = uint4{0u,0u,0u,0u};
        if (iy < HIN && ix < HIN) {
            const bf16* p = in + (((size_t)img_l * HIN + iy) * HIN + ix) * CIN + ic;
            v[0] = *(const uint4*)p;
            v[1] = *(const uint4*)(p + 8);
        }
    };
    auto writeA = [&](const uint4* v, int buf) {
        *(uint4*)&As[buf][ar][(2*ah)*8]   = v[0];
        *(uint4*)&As[buf][ar][(2*ah+1)*8] = v[1];
    };
    auto loadB = [&](int s, uint4& v) {
        int k = s*32 + bslot*8;
        int tap = k / CIN, ic = k % CIN;
        v = *(const uint4*)(wt + ((size_t)tap * COUT + nblk*64 + brow) * CIN + ic);
    };
    auto writeB = [&](uint4 v, int buf) {
        *(uint4*)&Bs[buf][brow][bslot*8] = v;
    };

    f32x4 acc[2][4];
    #pragma unroll
    for (int i = 0; i < 2; ++i)
        #pragma unroll
        for (int j = 0; j < 4; ++j) acc[i][j] = f32x4{0.f, 0.f, 0.f, 0.f};

    {   // prologue
        uint4 va[2]; uint4 vb;
        loadA(0, va); loadB(0, vb);
        writeA(va, 0); writeB(vb, 0);
    }
    __syncthreads();

    for (int s = 0; s < S; ++s) {
        int cur = s & 1;
        bool nxt = (s + 1 < S);
        uint4 va[2]; uint4 vb;
        if (nxt) { loadA(s + 1, va); loadB(s + 1, vb); }
        bf16x8 af[2], bfr[4];
        #pragma unroll
        for (int mi = 0; mi < 2; ++mi)
            af[mi] = *(const bf16x8*)&As[cur][wv*32 + mi*16 + (lane&15)][(lane>>4)*8];
        #pragma unroll
        for (int ni = 0; ni < 4; ++ni)
            bfr[ni] = *(const bf16x8*)&Bs[cur][ni*16 + (lane&15)][(lane>>4)*8];
        #pragma unroll
        for (int mi = 0; mi < 2; ++mi)
            #pragma unroll
            for (int ni = 0; ni < 4; ++ni)
                acc[mi][ni] = __builtin_amdgcn_mfma_f32_16x16x32_bf16(af[mi], bfr[ni], acc[mi][ni], 0, 0, 0);
        if (nxt) { writeA(va, cur ^ 1); writeB(vb, cur ^ 1); }
        __syncthreads();
    }

    if (!POOL) {
        #pragma unroll
        for (int ni = 0; ni < 4; ++ni) {
            int oc = nblk*64 + ni*16 + (lane & 15);
            float b = bias[oc];
            #pragma unroll
            for (int mi = 0; mi < 2; ++mi)
                #pragma unroll
                for (int rg = 0; rg < 4; ++rg) {
                    int rr = wv*32 + mi*16 + (lane>>4)*4 + rg;
                    int img_e, pos_e;
                    if (IMGS > 1) { img_e = bz*IMGS + rr/PPI; pos_e = rr % PPI; }
                    else          { img_e = bz; pos_e = bx*128 + rr; }
                    int oye = pos_e / HOUT, oxe = pos_e % HOUT;
                    float v = fmaxf(acc[mi][ni][rg] + b, 0.0f);
                    out[(((size_t)img_e * HOUT + oye) * HOUT + oxe) * COUT + oc] = __float2bfloat16(v);
                }
        }
    } else {
        #pragma unroll
        for (int ni = 0; ni < 4; ++ni) {
            int oc = nblk*64 + ni*16 + (lane & 15);
            float b = bias[oc];
            float s = 0.0f;
            #pragma unroll
            for (int mi = 0; mi < 2; ++mi)
                #pragma unroll
                for (int rg = 0; rg < 4; ++rg) s += fmaxf(acc[mi][ni][rg] + b, 0.0f);
            s += __shfl_xor(s, 16);
            s += __shfl_xor(s, 32);
            if (lane < 16) partial[wv][ni*16 + lane] = s;
        }
        __syncthreads();
        if (tid < 64 * IMGS) {
            int e = tid >> 6, c = tid & 63;
            float v = partial[2*e][c] + partial[2*e + 1][c];
            pooled[((size_t)(img0 + bz*IMGS + e)) * 256 + nblk*64 + c] = v * (1.0f/64.0f);
        }
    }
}

// ---- FC 256->128 per image ----
__global__ void fc_kernel(const float* __restrict__ pooled, const float* __restrict__ Wfc,
                          const float* __restrict__ bfc, float* __restrict__ z) {
    int n = blockIdx.x;    // 512
    int t = threadIdx.x;   // 128
    const float* hp = pooled + (size_t)n * 256;
    float acc = bfc[t];
    for (int k = 0; k < 256; ++k) acc = fmaf(hp[k], Wfc[(size_t)k*kLatent + t], acc);
    z[(size_t)n*kLatent + t] = acc;
}

// ---- mean over the 32 channel-images ----
__global__ void final_mean_kernel(const float* __restrict__ z, float* __restrict__ out) {
    int b = blockIdx.x;    // 16
    int l = threadIdx.x;   // 128
    float s = 0.0f;
    #pragma unroll
    for (int c = 0; c < kC; ++c) s += z[((size_t)(b*kC + c))*kLatent + l];
    out[(size_t)b*kLatent + l] = s * (1.0f/kC);
}

extern "C" void kernel_launch(void* const* d_in, const int* in_sizes, int n_in,
                              void* d_out, int out_size, void* d_ws, size_t ws_size,
                              hipStream_t stream) {
    const float* x_raw = (const float*)d_in[0];
    const float* W1 = (const float*)d_in[1];  const float* b1 = (const float*)d_in[2];
    const float* W2 = (const float*)d_in[3];  const float* b2 = (const float*)d_in[4];
    const float* W3 = (const float*)d_in[5];  const float* b3 = (const float*)d_in[6];
    const float* W4 = (const float*)d_in[7];  const float* b4 = (const float*)d_in[8];
    const float* Wfc = (const float*)d_in[9]; const float* bfc = (const float*)d_in[10];
    float* out = (float*)d_out;

    char* wsb = (char*)d_ws;
    float* xn     = (float*)(wsb);                      // 256 KiB
    float* sq     = (float*)(wsb + (256u<<10));         // 256 KiB
    float* z      = (float*)(wsb + (512u<<10));         // 256 KiB
    float* pooled = (float*)(wsb + (768u<<10));         // 512 KiB
    bf16* Wt2     = (bf16*)(wsb + (1280u<<10));         // 36 KiB
    bf16* Wt3     = (bf16*)(wsb + (1316u<<10));         // 144 KiB
    bf16* Wt4     = (bf16*)(wsb + (1460u<<10));         // 576 KiB
    bf16* W1b     = (bf16*)(wsb + (2036u<<10));         // 2 KiB
    char* chunk_base = wsb + (2048u<<10);               // 2 MiB header

    // Per-image: h2 NHWC bf16 128 KiB + h3 64 KiB (h1 never materialized)
    const size_t perH2 = 32u*32u*64u*2u, perH3 = 16u*16u*128u*2u;
    const size_t perImg = perH2 + perH3;
    int chunk = 4;
    for (int c = 512; c >= 4; c >>= 1) {
        if ((2048u<<10) + (size_t)c * perImg <= ws_size) { chunk = c; break; }
    }

    gaf_stats_kernel<<<kBC, kS, 0, stream>>>(x_raw, xn, sq);
    wtrans1_kernel<<<4, 256, 0, stream>>>(W1, W1b);
    wtrans_kernel<<<(9*64*32 + 255)/256, 256, 0, stream>>>(W2, Wt2, 64, 32);
    wtrans_kernel<<<(9*128*64 + 255)/256, 256, 0, stream>>>(W3, Wt3, 128, 64);
    wtrans_kernel<<<(9*256*128 + 255)/256, 256, 0, stream>>>(W4, Wt4, 256, 128);

    for (int img0 = 0; img0 < kBC; img0 += chunk) {
        int nimg = chunk;
        bf16* h2 = (bf16*)chunk_base;
        bf16* h3 = (bf16*)(chunk_base + (size_t)chunk * perH2);

        // fused conv1+conv2: 2->32->64, 128->64->32
        conv12_kernel<<<dim3(8, nimg), 256, 0, stream>>>(xn, sq, W1b, b1, Wt2, b2, h2, img0);
        // conv3: 64->128, 32->16 : M=256/img -> 2 mblk, N=128 -> 2 nblk
        conv_mfma_kernel<64, 128, 32, 1, false>
            <<<dim3(2, 2, nimg), 256, 0, stream>>>(h2, Wt3, b3, h3, nullptr, img0);
        // conv4: 128->256, 16->8 : 2 imgs/block (M=128), N=256 -> 4 nblk, fused pool
        conv_mfma_kernel<128, 256, 16, 2, true>
            <<<dim3(1, 4, nimg/2), 256, 0, stream>>>(h3, Wt4, b4, nullptr, pooled, img0);
    }

    fc_kernel<<<kBC, kLatent, 0, stream>>>(pooled, Wfc, bfc, z);
    final_mean_kernel<<<kB, kLatent, 0, stream>>>(z, out);
}

// Round 8
// 255.444 us; speedup vs baseline: 55.0745x; 1.0866x over previous
//
#include <hip/hip_runtime.h>
#include <hip/hip_bf16.h>

#define DEV __device__ __forceinline__

constexpr int kB = 16, kC = 32, kT = 512, kS = 128, kBC = 512, kLatent = 128;
constexpr float kEps = 1e-8f;

using bf16 = __hip_bfloat16;
using bf16x8 = __attribute__((ext_vector_type(8))) short;   // 8 bf16 = 4 VGPRs
using f32x4  = __attribute__((ext_vector_type(4))) float;

DEV unsigned short f2bf(float v) {
    bf16 h = __float2bfloat16(v);
    return *(unsigned short*)&h;
}

// async global->LDS, 16B per lane; LDS dest = wave-uniform base + lane*16
DEV void gld16(const void* g, void* l) {
    __builtin_amdgcn_global_load_lds(
        (const __attribute__((address_space(1))) unsigned*)g,
        (__attribute__((address_space(3))) unsigned*)l, 16, 0, 0);
}

// ---- per-(b,c) downsample + min/max normalize + sqrt term ----
__global__ void gaf_stats_kernel(const float* __restrict__ x_raw,
                                 float* __restrict__ xn, float* __restrict__ sq) {
    int bc = blockIdx.x;       // 512
    int s  = threadIdx.x;      // 128
    const float* xp = x_raw + (size_t)bc * kT;
    float v = 0.25f * (xp[4*s] + xp[4*s+1] + xp[4*s+2] + xp[4*s+3]);
    __shared__ float smn[kS], smx[kS];
    smn[s] = v; smx[s] = v;
    __syncthreads();
    for (int off = kS/2; off > 0; off >>= 1) {
        if (s < off) {
            smn[s] = fminf(smn[s], smn[s+off]);
            smx[s] = fmaxf(smx[s], smx[s+off]);
        }
        __syncthreads();
    }
    float mn = smn[0], mx = smx[0];
    float xv = 2.0f * (v - mn) / (mx - mn + kEps) - 1.0f;
    xv = fminf(fmaxf(xv, -1.0f), 1.0f);
    float sv = sqrtf(fminf(fmaxf(1.0f - xv*xv, 0.0f), 1.0f));
    xn[bc*kS + s] = xv;
    sq[bc*kS + s] = sv;
}

// ---- all weight transposes in ONE kernel ----
// W1b: [oc][32] (18 real + pad); Wt2/3/4: [tap][oc][ic] bf16
__global__ void wtrans_all_kernel(const float* __restrict__ w1,
                                  const float* __restrict__ w2,
                                  const float* __restrict__ w3,
                                  const float* __restrict__ w4,
                                  bf16* __restrict__ w1b, bf16* __restrict__ wt2,
                                  bf16* __restrict__ wt3, bf16* __restrict__ wt4) {
    int idx = blockIdx.x * blockDim.x + threadIdx.x;
    if (idx < 1024) {
        int oc = idx >> 5, k = idx & 31;
        w1b[idx] = __float2bfloat16(k < 18 ? w1[oc*18 + k] : 0.0f);
        return;
    }
    idx -= 1024;
    const float* src; bf16* dst; int CIN, COUT;
    if (idx < 18432)       { src = w2; dst = wt2; CIN = 32;  COUT = 64;  }
    else if (idx < 92160)  { idx -= 18432;  src = w3; dst = wt3; CIN = 64;  COUT = 128; }
    else if (idx < 387072) { idx -= 92160;  src = w4; dst = wt4; CIN = 128; COUT = 256; }
    else return;
    int ic = idx % CIN;
    int oc = (idx / CIN) % COUT;
    int t  = idx / (CIN * COUT);
    dst[((size_t)t * COUT + oc) * CIN + ic] = __float2bfloat16(src[((size_t)oc * CIN + ic) * 9 + t]);
}

// ---- FUSED conv1+conv2 (4 conv2-rows per block) ----
// Phase 1a: 18 GAF products per h1-position -> LDS (bf16, padded rows).
// Phase 1b: h1 = relu(G @ W1b^T + b1) via MFMA, written in-place (parity split).
// Phase 2: conv2 GEMM; B via async global_load_lds, triple-buffered (dist 2).
__global__ __launch_bounds__(256, 2)
void conv12_kernel(const float* __restrict__ xn, const float* __restrict__ sq,
                   const bf16* __restrict__ w1b, const float* __restrict__ b1,
                   const bf16* __restrict__ wt2, const float* __restrict__ b2,
                   bf16* __restrict__ out, int img0) {
    __shared__ float xl[kS], sl[kS];
    __shared__ __align__(16) union { short G[576][40]; short H[2][288][40]; } U; // 45 KiB
    __shared__ __align__(16) short Bs2[3][64][32];                               // 12 KiB
    __shared__ __align__(16) short W1s[32][40];                                  // 2.5 KiB

    int tid  = threadIdx.x;
    int lane = tid & 63;
    int wv   = tid >> 6;
    int mblk = blockIdx.x;   // 0..7 -> conv2 rows 4*mblk..4*mblk+3
    int bz   = blockIdx.y;   // chunk-local image
    int bc   = img0 + bz;

    // async prefetch conv2 B taps 0 and 1 (4 KiB each, lane-linear)
    gld16((const char*)wt2 + 0*4096 + tid*16, (char*)Bs2 + 0*4096 + tid*16);
    gld16((const char*)wt2 + 1*4096 + tid*16, (char*)Bs2 + 1*4096 + tid*16);

    if (tid < 128) {
        xl[tid] = xn[(size_t)bc * kS + tid];
        int rr = tid >> 2, sg = tid & 3;
        *(uint4*)&W1s[rr][sg*8] = *(const uint4*)(w1b + rr*32 + sg*8);
    } else {
        sl[tid - 128] = sq[(size_t)bc * kS + (tid - 128)];
    }
    __syncthreads();

    // ---- Phase 1a: G rows for h1 tile rows iy = 8*mblk .. 8*mblk+8 ----
    #pragma unroll
    for (int it = 0; it < 3; ++it) {
        int idx = it * 256 + tid;
        if (idx >= 576) break;
        int trow = idx >> 6, hx = idx & 63;
        int iy = 8 * mblk + trow;
        unsigned int pk[16];
        #pragma unroll
        for (int j = 0; j < 16; ++j) pk[j] = 0u;
        if (iy < 64) {
            float xr[3], sr[3], xc[3], sc[3];
            #pragma unroll
            for (int k = 0; k < 3; ++k) {
                int iyy = 2*iy + k, ixx = 2*hx + k;
                bool vy = iyy < kS, vx = ixx < kS;
                xr[k] = vy ? xl[iyy] : 0.0f;  sr[k] = vy ? sl[iyy] : 0.0f;
                xc[k] = vx ? xl[ixx] : 0.0f;  sc[k] = vx ? sl[ixx] : 0.0f;
            }
            unsigned short gs[18];
            #pragma unroll
            for (int ky = 0; ky < 3; ++ky)
                #pragma unroll
                for (int kx = 0; kx < 3; ++kx) {
                    gs[ky*3+kx]   = f2bf(xr[ky]*xc[kx] - sr[ky]*sc[kx]);  // gasf
                    gs[9+ky*3+kx] = f2bf(sr[ky]*xc[kx] - xr[ky]*sc[kx]);  // gadf
                }
            #pragma unroll
            for (int j = 0; j < 9; ++j)
                pk[j] = (unsigned int)gs[2*j] | ((unsigned int)gs[2*j+1] << 16);
        }
        #pragma unroll
        for (int j = 0; j < 4; ++j) *(uint4*)&U.G[idx][j*8] = ((uint4*)pk)[j];
    }
    __syncthreads();

    // ---- Phase 1b: h1 = relu(G @ W1b^T + b1) via MFMA ----
    f32x4 c1[9][2];
    bf16x8 w1f0 = *(const bf16x8*)&W1s[(lane & 15)][(lane>>4)*8];
    bf16x8 w1f1 = *(const bf16x8*)&W1s[16 + (lane & 15)][(lane>>4)*8];
    #pragma unroll
    for (int j = 0; j < 9; ++j) {
        int mt = 4*j + wv;   // 0..35
        bf16x8 af = *(const bf16x8*)&U.G[mt*16 + (lane & 15)][(lane>>4)*8];
        f32x4 zz = f32x4{0.f, 0.f, 0.f, 0.f};
        c1[j][0] = __builtin_amdgcn_mfma_f32_16x16x32_bf16(af, w1f0, zz, 0, 0, 0);
        c1[j][1] = __builtin_amdgcn_mfma_f32_16x16x32_bf16(af, w1f1, zz, 0, 0, 0);
    }
    __syncthreads();   // all G reads complete before overwrite

    #pragma unroll
    for (int j = 0; j < 9; ++j) {
        int mt = 4*j + wv;
        #pragma unroll
        for (int h = 0; h < 2; ++h) {
            int oc = h*16 + (lane & 15);
            float bb = b1[oc];
            #pragma unroll
            for (int rg = 0; rg < 4; ++rg) {
                int pos = mt*16 + (lane>>4)*4 + rg;
                int trow = pos >> 6, hx = pos & 63;
                float v = fmaxf(c1[j][h][rg] + bb, 0.0f);
                if (8*mblk + trow >= 64) v = 0.0f;   // SAME padding row
                U.H[hx & 1][trow*32 + (hx >> 1)][oc] = (short)f2bf(v);
            }
        }
    }
    __syncthreads();

    // ---- Phase 2: conv2 GEMM, K = 9 taps x 32 ic; B async triple-buffered ----
    f32x4 acc[2][4];
    #pragma unroll
    for (int i = 0; i < 2; ++i)
        #pragma unroll
        for (int j = 0; j < 4; ++j) acc[i][j] = f32x4{0.f, 0.f, 0.f, 0.f};

    for (int tap = 0; tap < 9; ++tap) {
        if (tap + 2 < 9)
            gld16((const char*)wt2 + (tap+2)*4096 + tid*16,
                  (char*)Bs2 + ((tap+2)%3)*4096 + tid*16);
        int ky = tap / 3, kx = tap % 3;
        int trow = 2*wv + ky;
        const short* bsl = &Bs2[tap%3][0][0];
        bf16x8 af[2], bfr[4];
        #pragma unroll
        for (int mi = 0; mi < 2; ++mi) {
            int ocol = mi*16 + (lane & 15);
            int x = 2*ocol + kx;
            bf16x8 z = {0,0,0,0,0,0,0,0};
            af[mi] = (x < 64) ? *(const bf16x8*)&U.H[kx & 1][trow*32 + (x>>1)][(lane>>4)*8] : z;
        }
        #pragma unroll
        for (int ni = 0; ni < 4; ++ni)
            bfr[ni] = *(const bf16x8*)&bsl[(ni*16 + (lane&15))*32 + (lane>>4)*8];
        #pragma unroll
        for (int mi = 0; mi < 2; ++mi)
            #pragma unroll
            for (int ni = 0; ni < 4; ++ni)
                acc[mi][ni] = __builtin_amdgcn_mfma_f32_16x16x32_bf16(af[mi], bfr[ni], acc[mi][ni], 0, 0, 0);
        __syncthreads();
    }

    // ---- epilogue: h2 NHWC [bz][32][32][64] ----
    int oy = 4*mblk + wv;
    #pragma unroll
    for (int ni = 0; ni < 4; ++ni) {
        int oc = ni*16 + (lane & 15);
        float b = b2[oc];
        #pragma unroll
        for (int mi = 0; mi < 2; ++mi)
            #pragma unroll
            for (int rg = 0; rg < 4; ++rg) {
                int ocol = 16*mi + (lane>>4)*4 + rg;
                float v = fmaxf(acc[mi][ni][rg] + b, 0.0f);
                out[(((size_t)bz*32 + oy)*32 + ocol)*64 + oc] = __float2bfloat16(v);
            }
    }
}

// ---- MFMA implicit-GEMM conv (conv3/conv4), async global_load_lds staging ----
// Block 128M x 128N, 2x2 waves (wave 64x64, acc 4x4), BK=32 double-buffered,
// 16 MFMA + 8 ds_read_b128 per wave per barrier. Unpadded 64B LDS rows.
// Invalid taps read from a zeroed scratch line (address select, all lanes active).
template<int CIN, int COUT, int HIN, int IMGS, bool POOL>
__global__ __launch_bounds__(256, 4)
void conv_mfma_kernel(const bf16* __restrict__ in, const bf16* __restrict__ wt,
                      const float* __restrict__ bias, bf16* __restrict__ out,
                      float* __restrict__ pooled, int img0,
                      const bf16* __restrict__ zbuf) {
    constexpr int HOUT = HIN / 2;
    constexpr int PPI  = HOUT * HOUT;
    constexpr int K    = 9 * CIN;
    constexpr int S    = K / 32;
    constexpr int TPC  = CIN / 32;          // stages per tap
    __shared__ __align__(16) short As[2*128*32];   // 16 KiB
    __shared__ __align__(16) short Bs[2*128*32];   // 16 KiB

    int tid  = threadIdx.x;
    int lane = tid & 63;
    int wv   = tid >> 6;
    int wm   = wv >> 1, wn = wv & 1;
    int bx   = blockIdx.x;
    int nblk = blockIdx.y;
    int bz   = blockIdx.z;

    int rsub = lane >> 2, seg = lane & 3;
    int imgA[2], oyA[2], oxA[2], rB[2];
    #pragma unroll
    for (int j = 0; j < 2; ++j) {
        int r = (wv*2 + j)*16 + rsub;       // 0..127
        int il, pos;
        if (IMGS > 1) { il = bz*IMGS + r/PPI; pos = r % PPI; }
        else          { il = bz; pos = bx*128 + r; }
        imgA[j] = il; oyA[j] = pos / HOUT; oxA[j] = pos % HOUT;
        rB[j] = r;
    }

    auto issue = [&](int s, int nb) {
        int tap = s / TPC, icb = (s % TPC) * 32;
        int ky = tap / 3, kx = tap % 3;
        #pragma unroll
        for (int j = 0; j < 2; ++j) {
            int iy = 2*oyA[j] + ky, ix = 2*oxA[j] + kx;
            const bf16* ga = (iy < HIN && ix < HIN)
                ? in + (((size_t)imgA[j]*HIN + iy)*HIN + ix)*CIN + icb + seg*8
                : zbuf + seg*8;
            gld16(ga, (char*)As + nb*8192 + (wv*2 + j)*1024 + lane*16);
            const bf16* gb = wt + ((size_t)tap*COUT + nblk*128 + rB[j])*CIN + icb + seg*8;
            gld16(gb, (char*)Bs + nb*8192 + (wv*2 + j)*1024 + lane*16);
        }
    };

    f32x4 acc[4][4];
    #pragma unroll
    for (int i = 0; i < 4; ++i)
        #pragma unroll
        for (int j = 0; j < 4; ++j) acc[i][j] = f32x4{0.f, 0.f, 0.f, 0.f};

    issue(0, 0);
    __syncthreads();

    for (int s = 0; s < S; ++s) {
        int cur = s & 1;
        if (s + 1 < S) issue(s + 1, cur ^ 1);
        bf16x8 af[4], bfr[4];
        #pragma unroll
        for (int mi = 0; mi < 4; ++mi)
            af[mi] = *(const bf16x8*)&As[cur*4096 + (wm*64 + mi*16 + (lane&15))*32 + (lane>>4)*8];
        #pragma unroll
        for (int ni = 0; ni < 4; ++ni)
            bfr[ni] = *(const bf16x8*)&Bs[cur*4096 + (wn*64 + ni*16 + (lane&15))*32 + (lane>>4)*8];
        #pragma unroll
        for (int mi = 0; mi < 4; ++mi)
            #pragma unroll
            for (int ni = 0; ni < 4; ++ni)
                acc[mi][ni] = __builtin_amdgcn_mfma_f32_16x16x32_bf16(af[mi], bfr[ni], acc[mi][ni], 0, 0, 0);
        __syncthreads();
    }

    // Epilogue. C/D layout: col = lane&15 (N), row = (lane>>4)*4 + rg (M).
    if (!POOL) {
        #pragma unroll
        for (int ni = 0; ni < 4; ++ni) {
            int oc = nblk*128 + wn*64 + ni*16 + (lane & 15);
            float b = bias[oc];
            #pragma unroll
            for (int mi = 0; mi < 4; ++mi)
                #pragma unroll
                for (int rg = 0; rg < 4; ++rg) {
                    int rr = wm*64 + mi*16 + (lane>>4)*4 + rg;
                    int img_e, pos_e;
                    if (IMGS > 1) { img_e = bz*IMGS + rr/PPI; pos_e = rr % PPI; }
                    else          { img_e = bz; pos_e = bx*128 + rr; }
                    int oye = pos_e / HOUT, oxe = pos_e % HOUT;
                    float v = fmaxf(acc[mi][ni][rg] + b, 0.0f);
                    out[(((size_t)img_e * HOUT + oye) * HOUT + oxe) * COUT + oc] = __float2bfloat16(v);
                }
        }
    } else {
        // wave (wm) covers exactly image bz*IMGS + wm's 64 positions
        int img_e = bz*IMGS + wm;
        #pragma unroll
        for (int ni = 0; ni < 4; ++ni) {
            int oc = nblk*128 + wn*64 + ni*16 + (lane & 15);
            float b = bias[oc];
            float s = 0.0f;
            #pragma unroll
            for (int mi = 0; mi < 4; ++mi)
                #pragma unroll
                for (int rg = 0; rg < 4; ++rg) s += fmaxf(acc[mi][ni][rg] + b, 0.0f);
            s += __shfl_xor(s, 16);
            s += __shfl_xor(s, 32);
            if (lane < 16)
                pooled[((size_t)(img0 + img_e))*256 + nblk*128 + wn*64 + ni*16 + lane] = s * (1.0f/64.0f);
        }
    }
}

// ---- fused: mean over C (commutes with linear FC) + FC 256->128 ----
__global__ void poolfc_kernel(const float* __restrict__ pooled, const float* __restrict__ Wfc,
                              const float* __restrict__ bfc, float* __restrict__ out) {
    int b = blockIdx.x;    // 16
    int t = threadIdx.x;   // 128
    __shared__ float pm[256];
    #pragma unroll
    for (int q = 0; q < 2; ++q) {
        int k = q*128 + t;
        float s = 0.0f;
        #pragma unroll
        for (int c = 0; c < kC; ++c) s += pooled[((size_t)(b*kC + c))*256 + k];
        pm[k] = s * (1.0f/kC);
    }
    __syncthreads();
    float acc = bfc[t];
    for (int k = 0; k < 256; ++k) acc = fmaf(pm[k], Wfc[(size_t)k*kLatent + t], acc);
    out[(size_t)b*kLatent + t] = acc;
}

extern "C" void kernel_launch(void* const* d_in, const int* in_sizes, int n_in,
                              void* d_out, int out_size, void* d_ws, size_t ws_size,
                              hipStream_t stream) {
    const float* x_raw = (const float*)d_in[0];
    const float* W1 = (const float*)d_in[1];  const float* b1 = (const float*)d_in[2];
    const float* W2 = (const float*)d_in[3];  const float* b2 = (const float*)d_in[4];
    const float* W3 = (const float*)d_in[5];  const float* b3 = (const float*)d_in[6];
    const float* W4 = (const float*)d_in[7];  const float* b4 = (const float*)d_in[8];
    const float* Wfc = (const float*)d_in[9]; const float* bfc = (const float*)d_in[10];
    float* out = (float*)d_out;

    char* wsb = (char*)d_ws;
    float* xn     = (float*)(wsb);                      // 256 KiB
    float* sq     = (float*)(wsb + (256u<<10));         // 256 KiB
    float* pooled = (float*)(wsb + (512u<<10));         // 512 KiB
    bf16* Wt2     = (bf16*)(wsb + (1280u<<10));         // 36 KiB
    bf16* Wt3     = (bf16*)(wsb + (1316u<<10));         // 144 KiB
    bf16* Wt4     = (bf16*)(wsb + (1460u<<10));         // 576 KiB
    bf16* W1b     = (bf16*)(wsb + (2036u<<10));         // 2 KiB
    bf16* zbuf    = (bf16*)(wsb + (2040u<<10));         // 1 KiB (zeroed below)
    char* chunk_base = wsb + (2048u<<10);               // 2 MiB header

    const size_t perH2 = 32u*32u*64u*2u, perH3 = 16u*16u*128u*2u;
    const size_t perImg = perH2 + perH3;
    int chunk = 4;
    for (int c = 512; c >= 4; c >>= 1) {
        if ((2048u<<10) + (size_t)c * perImg <= ws_size) { chunk = c; break; }
    }

    hipMemsetAsync(zbuf, 0, 1024, stream);   // async, graph-capture safe
    gaf_stats_kernel<<<kBC, kS, 0, stream>>>(x_raw, xn, sq);
    wtrans_all_kernel<<<(388096 + 255)/256, 256, 0, stream>>>(W1, W2, W3, W4, W1b, Wt2, Wt3, Wt4);

    for (int img0 = 0; img0 < kBC; img0 += chunk) {
        int nimg = chunk;
        bf16* h2 = (bf16*)chunk_base;
        bf16* h3 = (bf16*)(chunk_base + (size_t)chunk * perH2);

        // fused conv1+conv2: 2->32->64, 128->64->32
        conv12_kernel<<<dim3(8, nimg), 256, 0, stream>>>(xn, sq, W1b, b1, Wt2, b2, h2, img0);
        // conv3: 64->128, 32->16 : M=256/img -> 2 mblk, N=128 (one tile)
        conv_mfma_kernel<64, 128, 32, 1, false>
            <<<dim3(2, 1, nimg), 256, 0, stream>>>(h2, Wt3, b3, h3, nullptr, img0, zbuf);
        // conv4: 128->256, 16->8 : 2 imgs/block (M=128), N=256 -> 2 nblk, fused pool
        conv_mfma_kernel<128, 256, 16, 2, true>
            <<<dim3(1, 2, nimg/2), 256, 0, stream>>>(h3, Wt4, b4, nullptr, pooled, img0, zbuf);
    }

    poolfc_kernel<<<kB, kLatent, 0, stream>>>(pooled, Wfc, bfc, out);
}

// Round 9
// 244.414 us; speedup vs baseline: 57.5599x; 1.0451x over previous
//
#include <hip/hip_runtime.h>
#include <hip/hip_bf16.h>

#define DEV __device__ __forceinline__

constexpr int kB = 16, kC = 32, kT = 512, kS = 128, kBC = 512, kLatent = 128;
constexpr float kEps = 1e-8f;

using bf16 = __hip_bfloat16;
using bf16x8 = __attribute__((ext_vector_type(8))) short;   // 8 bf16 = 4 VGPRs
using f32x4  = __attribute__((ext_vector_type(4))) float;

DEV unsigned short f2bf(float v) {
    bf16 h = __float2bfloat16(v);
    return *(unsigned short*)&h;
}

// async global->LDS, 16B per lane; LDS dest = wave-uniform base + lane*16
DEV void gld16(const void* g, void* l) {
    __builtin_amdgcn_global_load_lds(
        (const __attribute__((address_space(1))) unsigned*)g,
        (__attribute__((address_space(3))) unsigned*)l, 16, 0, 0);
}

// ---- per-(b,c) downsample + min/max normalize + sqrt term ----
__global__ void gaf_stats_kernel(const float* __restrict__ x_raw,
                                 float* __restrict__ xn, float* __restrict__ sq) {
    int bc = blockIdx.x;       // 512
    int s  = threadIdx.x;      // 128
    const float* xp = x_raw + (size_t)bc * kT;
    float v = 0.25f * (xp[4*s] + xp[4*s+1] + xp[4*s+2] + xp[4*s+3]);
    __shared__ float smn[kS], smx[kS];
    smn[s] = v; smx[s] = v;
    __syncthreads();
    for (int off = kS/2; off > 0; off >>= 1) {
        if (s < off) {
            smn[s] = fminf(smn[s], smn[s+off]);
            smx[s] = fmaxf(smx[s], smx[s+off]);
        }
        __syncthreads();
    }
    float mn = smn[0], mx = smx[0];
    float xv = 2.0f * (v - mn) / (mx - mn + kEps) - 1.0f;
    xv = fminf(fmaxf(xv, -1.0f), 1.0f);
    float sv = sqrtf(fminf(fmaxf(1.0f - xv*xv, 0.0f), 1.0f));
    xn[bc*kS + s] = xv;
    sq[bc*kS + s] = sv;
}

// ---- all weight transposes in ONE kernel ----
__global__ void wtrans_all_kernel(const float* __restrict__ w1,
                                  const float* __restrict__ w2,
                                  const float* __restrict__ w3,
                                  const float* __restrict__ w4,
                                  bf16* __restrict__ w1b, bf16* __restrict__ wt2,
                                  bf16* __restrict__ wt3, bf16* __restrict__ wt4) {
    int idx = blockIdx.x * blockDim.x + threadIdx.x;
    if (idx < 1024) {
        int oc = idx >> 5, k = idx & 31;
        w1b[idx] = __float2bfloat16(k < 18 ? w1[oc*18 + k] : 0.0f);
        return;
    }
    idx -= 1024;
    const float* src; bf16* dst; int CIN, COUT;
    if (idx < 18432)       { src = w2; dst = wt2; CIN = 32;  COUT = 64;  }
    else if (idx < 92160)  { idx -= 18432;  src = w3; dst = wt3; CIN = 64;  COUT = 128; }
    else if (idx < 387072) { idx -= 92160;  src = w4; dst = wt4; CIN = 128; COUT = 256; }
    else return;
    int ic = idx % CIN;
    int oc = (idx / CIN) % COUT;
    int t  = idx / (CIN * COUT);
    dst[((size_t)t * COUT + oc) * CIN + ic] = __float2bfloat16(src[((size_t)oc * CIN + ic) * 9 + t]);
}

// ---- FUSED conv1+conv2 (unchanged from round 8) ----
__global__ __launch_bounds__(256, 2)
void conv12_kernel(const float* __restrict__ xn, const float* __restrict__ sq,
                   const bf16* __restrict__ w1b, const float* __restrict__ b1,
                   const bf16* __restrict__ wt2, const float* __restrict__ b2,
                   bf16* __restrict__ out, int img0) {
    __shared__ float xl[kS], sl[kS];
    __shared__ __align__(16) union { short G[576][40]; short H[2][288][40]; } U;
    __shared__ __align__(16) short Bs2[3][64][32];
    __shared__ __align__(16) short W1s[32][40];

    int tid  = threadIdx.x;
    int lane = tid & 63;
    int wv   = tid >> 6;
    int mblk = blockIdx.x;
    int bz   = blockIdx.y;
    int bc   = img0 + bz;

    gld16((const char*)wt2 + 0*4096 + tid*16, (char*)Bs2 + 0*4096 + tid*16);
    gld16((const char*)wt2 + 1*4096 + tid*16, (char*)Bs2 + 1*4096 + tid*16);

    if (tid < 128) {
        xl[tid] = xn[(size_t)bc * kS + tid];
        int rr = tid >> 2, sg = tid & 3;
        *(uint4*)&W1s[rr][sg*8] = *(const uint4*)(w1b + rr*32 + sg*8);
    } else {
        sl[tid - 128] = sq[(size_t)bc * kS + (tid - 128)];
    }
    __syncthreads();

    #pragma unroll
    for (int it = 0; it < 3; ++it) {
        int idx = it * 256 + tid;
        if (idx >= 576) break;
        int trow = idx >> 6, hx = idx & 63;
        int iy = 8 * mblk + trow;
        unsigned int pk[16];
        #pragma unroll
        for (int j = 0; j < 16; ++j) pk[j] = 0u;
        if (iy < 64) {
            float xr[3], sr[3], xc[3], sc[3];
            #pragma unroll
            for (int k = 0; k < 3; ++k) {
                int iyy = 2*iy + k, ixx = 2*hx + k;
                bool vy = iyy < kS, vx = ixx < kS;
                xr[k] = vy ? xl[iyy] : 0.0f;  sr[k] = vy ? sl[iyy] : 0.0f;
                xc[k] = vx ? xl[ixx] : 0.0f;  sc[k] = vx ? sl[ixx] : 0.0f;
            }
            unsigned short gs[18];
            #pragma unroll
            for (int ky = 0; ky < 3; ++ky)
                #pragma unroll
                for (int kx = 0; kx < 3; ++kx) {
                    gs[ky*3+kx]   = f2bf(xr[ky]*xc[kx] - sr[ky]*sc[kx]);
                    gs[9+ky*3+kx] = f2bf(sr[ky]*xc[kx] - xr[ky]*sc[kx]);
                }
            #pragma unroll
            for (int j = 0; j < 9; ++j)
                pk[j] = (unsigned int)gs[2*j] | ((unsigned int)gs[2*j+1] << 16);
        }
        #pragma unroll
        for (int j = 0; j < 4; ++j) *(uint4*)&U.G[idx][j*8] = ((uint4*)pk)[j];
    }
    __syncthreads();

    f32x4 c1[9][2];
    bf16x8 w1f0 = *(const bf16x8*)&W1s[(lane & 15)][(lane>>4)*8];
    bf16x8 w1f1 = *(const bf16x8*)&W1s[16 + (lane & 15)][(lane>>4)*8];
    #pragma unroll
    for (int j = 0; j < 9; ++j) {
        int mt = 4*j + wv;
        bf16x8 af = *(const bf16x8*)&U.G[mt*16 + (lane & 15)][(lane>>4)*8];
        f32x4 zz = f32x4{0.f, 0.f, 0.f, 0.f};
        c1[j][0] = __builtin_amdgcn_mfma_f32_16x16x32_bf16(af, w1f0, zz, 0, 0, 0);
        c1[j][1] = __builtin_amdgcn_mfma_f32_16x16x32_bf16(af, w1f1, zz, 0, 0, 0);
    }
    __syncthreads();

    #pragma unroll
    for (int j = 0; j < 9; ++j) {
        int mt = 4*j + wv;
        #pragma unroll
        for (int h = 0; h < 2; ++h) {
            int oc = h*16 + (lane & 15);
            float bb = b1[oc];
            #pragma unroll
            for (int rg = 0; rg < 4; ++rg) {
                int pos = mt*16 + (lane>>4)*4 + rg;
                int trow = pos >> 6, hx = pos & 63;
                float v = fmaxf(c1[j][h][rg] + bb, 0.0f);
                if (8*mblk + trow >= 64) v = 0.0f;
                U.H[hx & 1][trow*32 + (hx >> 1)][oc] = (short)f2bf(v);
            }
        }
    }
    __syncthreads();

    f32x4 acc[2][4];
    #pragma unroll
    for (int i = 0; i < 2; ++i)
        #pragma unroll
        for (int j = 0; j < 4; ++j) acc[i][j] = f32x4{0.f, 0.f, 0.f, 0.f};

    for (int tap = 0; tap < 9; ++tap) {
        if (tap + 2 < 9)
            gld16((const char*)wt2 + (tap+2)*4096 + tid*16,
                  (char*)Bs2 + ((tap+2)%3)*4096 + tid*16);
        int ky = tap / 3, kx = tap % 3;
        int trow = 2*wv + ky;
        const short* bsl = &Bs2[tap%3][0][0];
        bf16x8 af[2], bfr[4];
        #pragma unroll
        for (int mi = 0; mi < 2; ++mi) {
            int ocol = mi*16 + (lane & 15);
            int x = 2*ocol + kx;
            bf16x8 z = {0,0,0,0,0,0,0,0};
            af[mi] = (x < 64) ? *(const bf16x8*)&U.H[kx & 1][trow*32 + (x>>1)][(lane>>4)*8] : z;
        }
        #pragma unroll
        for (int ni = 0; ni < 4; ++ni)
            bfr[ni] = *(const bf16x8*)&bsl[(ni*16 + (lane&15))*32 + (lane>>4)*8];
        #pragma unroll
        for (int mi = 0; mi < 2; ++mi)
            #pragma unroll
            for (int ni = 0; ni < 4; ++ni)
                acc[mi][ni] = __builtin_amdgcn_mfma_f32_16x16x32_bf16(af[mi], bfr[ni], acc[mi][ni], 0, 0, 0);
        __syncthreads();
    }

    int oy = 4*mblk + wv;
    #pragma unroll
    for (int ni = 0; ni < 4; ++ni) {
        int oc = ni*16 + (lane & 15);
        float b = b2[oc];
        #pragma unroll
        for (int mi = 0; mi < 2; ++mi)
            #pragma unroll
            for (int rg = 0; rg < 4; ++rg) {
                int ocol = 16*mi + (lane>>4)*4 + rg;
                float v = fmaxf(acc[mi][ni][rg] + b, 0.0f);
                out[(((size_t)bz*32 + oy)*32 + ocol)*64 + oc] = __float2bfloat16(v);
            }
    }
}

// ---- FUSED conv3+conv4: one block per image; h3 lives in LDS only ----
// Phase 1 (conv3): M=256 (16x16 pos) x N=128, K=576, BK=32, 18 dbuf stages via
//   gld16; wave tile 64M x 128N (acc[4][8], 32 MFMA/wave/stage).
//   h3 = relu(.) written to LDS, layout [pos][chunk^((pos>>1)&7)] (2-way reads).
// Phase 2 (conv4): M=64, N=256, K=1152, 36 stages; A from h3-LDS, B (wt4)
//   streamed via gld16 (L2-hot). Fused global-avg-pool epilogue -> pooled.
__global__ __launch_bounds__(256)
void conv34_kernel(const bf16* __restrict__ h2, const bf16* __restrict__ wt3,
                   const float* __restrict__ b3, const bf16* __restrict__ wt4,
                   const float* __restrict__ b4, float* __restrict__ pooled,
                   int img0, const bf16* __restrict__ zbuf) {
    __shared__ __align__(16) short H3[257*128];   // 64.25 KiB: [pos 0..256][16 chunks x 8 sh]
    __shared__ __align__(16) short stA[2*256*32]; // 32 KiB: phase1 A / phase2 B
    __shared__ __align__(16) short stB[2*128*32]; // 16 KiB: phase1 B

    int tid  = threadIdx.x;
    int lane = tid & 63;
    int wv   = tid >> 6;
    int img  = blockIdx.x;          // chunk-local image

    // zero line (pos=256) for invalid phase-2 taps
    if (tid < 128) H3[256*128 + tid] = 0;

    // ---- Phase 1: conv3 ----
    auto issue1 = [&](int s, int buf) {
        int tap = s >> 1, icb = (s & 1) * 32;
        int ky = tap / 3, kx = tap % 3;
        #pragma unroll
        for (int j = 0; j < 4; ++j) {
            int row = wv*64 + j*16 + (lane >> 2);
            int oy = row >> 4, ox = row & 15;
            int iy = 2*oy + ky, ix = 2*ox + kx;
            const bf16* src = (iy < 32 && ix < 32)
                ? h2 + (((size_t)img*32 + iy)*32 + ix)*64 + icb + (lane & 3)*8
                : zbuf + (lane & 3)*8;
            gld16(src, (char*)&stA[buf*8192 + (wv*64 + j*16)*32] + lane*16);
        }
        #pragma unroll
        for (int j = 0; j < 2; ++j) {
            int brow = wv*32 + j*16 + (lane >> 2);
            const bf16* src = wt3 + ((size_t)tap*128 + brow)*64 + icb + (lane & 3)*8;
            gld16(src, (char*)&stB[buf*4096 + (wv*32 + j*16)*32] + lane*16);
        }
    };

    f32x4 acc[4][8];
    #pragma unroll
    for (int i = 0; i < 4; ++i)
        #pragma unroll
        for (int j = 0; j < 8; ++j) acc[i][j] = f32x4{0.f, 0.f, 0.f, 0.f};

    issue1(0, 0);
    __syncthreads();

    for (int s = 0; s < 18; ++s) {
        int cur = s & 1;
        if (s + 1 < 18) issue1(s + 1, cur ^ 1);
        bf16x8 af[4];
        #pragma unroll
        for (int mi = 0; mi < 4; ++mi)
            af[mi] = *(const bf16x8*)&stA[cur*8192 + (wv*64 + mi*16 + (lane&15))*32 + (lane>>4)*8];
        #pragma unroll
        for (int ni = 0; ni < 8; ++ni) {
            bf16x8 bfr = *(const bf16x8*)&stB[cur*4096 + (ni*16 + (lane&15))*32 + (lane>>4)*8];
            #pragma unroll
            for (int mi = 0; mi < 4; ++mi)
                acc[mi][ni] = __builtin_amdgcn_mfma_f32_16x16x32_bf16(af[mi], bfr, acc[mi][ni], 0, 0, 0);
        }
        __syncthreads();
    }

    // h3 -> LDS (relu + bias), swizzled chunks
    #pragma unroll
    for (int ni = 0; ni < 8; ++ni) {
        int oc = ni*16 + (lane & 15);
        float bb = b3[oc];
        int q = oc >> 3, ql = oc & 7;
        #pragma unroll
        for (int mi = 0; mi < 4; ++mi)
            #pragma unroll
            for (int rg = 0; rg < 4; ++rg) {
                int pos = wv*64 + mi*16 + (lane>>4)*4 + rg;
                float v = fmaxf(acc[mi][ni][rg] + bb, 0.0f);
                H3[pos*128 + (q ^ ((pos>>1)&7))*8 + ql] = (short)f2bf(v);
            }
    }

    // ---- Phase 2: conv4 ----
    auto issue2 = [&](int s, int buf) {
        int tap = s >> 2, icb = (s & 3) * 32;
        #pragma unroll
        for (int j = 0; j < 4; ++j) {
            int brow = wv*64 + j*16 + (lane >> 2);
            const bf16* src = wt4 + ((size_t)tap*256 + brow)*128 + icb + (lane & 3)*8;
            gld16(src, (char*)&stA[buf*8192 + (wv*64 + j*16)*32] + lane*16);
        }
    };

    issue2(0, 0);
    __syncthreads();   // h3 writes visible + B stage 0 loaded

    f32x4 ac4[4][4];
    #pragma unroll
    for (int i = 0; i < 4; ++i)
        #pragma unroll
        for (int j = 0; j < 4; ++j) ac4[i][j] = f32x4{0.f, 0.f, 0.f, 0.f};

    for (int s = 0; s < 36; ++s) {
        int cur = s & 1;
        if (s + 1 < 36) issue2(s + 1, cur ^ 1);
        int tap = s >> 2, kq0 = (s & 3) * 4 + (lane >> 4);
        int ky = tap / 3, kx = tap % 3;
        bf16x8 af[4];
        #pragma unroll
        for (int mi = 0; mi < 4; ++mi) {
            int m = mi*16 + (lane & 15);
            int oy = m >> 3, ox = m & 7;
            int iy = 2*oy + ky, ix = 2*ox + kx;
            int pos = (iy < 16 && ix < 16) ? iy*16 + ix : 256;
            af[mi] = *(const bf16x8*)&H3[pos*128 + (kq0 ^ ((pos>>1)&7))*8];
        }
        #pragma unroll
        for (int ni = 0; ni < 4; ++ni) {
            bf16x8 bfr = *(const bf16x8*)&stA[cur*8192 + (wv*64 + ni*16 + (lane&15))*32 + (lane>>4)*8];
            #pragma unroll
            for (int mi = 0; mi < 4; ++mi)
                ac4[mi][ni] = __builtin_amdgcn_mfma_f32_16x16x32_bf16(af[mi], bfr, ac4[mi][ni], 0, 0, 0);
        }
        __syncthreads();
    }

    // fused global-avg-pool: wave wv owns oc slice [wv*64, wv*64+64)
    #pragma unroll
    for (int ni = 0; ni < 4; ++ni) {
        int oc = wv*64 + ni*16 + (lane & 15);
        float bb = b4[oc];
        float ssum = 0.0f;
        #pragma unroll
        for (int mi = 0; mi < 4; ++mi)
            #pragma unroll
            for (int rg = 0; rg < 4; ++rg) ssum += fmaxf(ac4[mi][ni][rg] + bb, 0.0f);
        ssum += __shfl_xor(ssum, 16);
        ssum += __shfl_xor(ssum, 32);
        if (lane < 16)
            pooled[((size_t)(img0 + img))*256 + wv*64 + ni*16 + lane] = ssum * (1.0f/64.0f);
    }
}

// ---- fused: mean over C (commutes with linear FC) + FC 256->128 ----
__global__ void poolfc_kernel(const float* __restrict__ pooled, const float* __restrict__ Wfc,
                              const float* __restrict__ bfc, float* __restrict__ out) {
    int b = blockIdx.x;    // 16
    int t = threadIdx.x;   // 128
    __shared__ float pm[256];
    #pragma unroll
    for (int q = 0; q < 2; ++q) {
        int k = q*128 + t;
        float s = 0.0f;
        #pragma unroll
        for (int c = 0; c < kC; ++c) s += pooled[((size_t)(b*kC + c))*256 + k];
        pm[k] = s * (1.0f/kC);
    }
    __syncthreads();
    float acc = bfc[t];
    for (int k = 0; k < 256; ++k) acc = fmaf(pm[k], Wfc[(size_t)k*kLatent + t], acc);
    out[(size_t)b*kLatent + t] = acc;
}

extern "C" void kernel_launch(void* const* d_in, const int* in_sizes, int n_in,
                              void* d_out, int out_size, void* d_ws, size_t ws_size,
                              hipStream_t stream) {
    const float* x_raw = (const float*)d_in[0];
    const float* W1 = (const float*)d_in[1];  const float* b1 = (const float*)d_in[2];
    const float* W2 = (const float*)d_in[3];  const float* b2 = (const float*)d_in[4];
    const float* W3 = (const float*)d_in[5];  const float* b3 = (const float*)d_in[6];
    const float* W4 = (const float*)d_in[7];  const float* b4 = (const float*)d_in[8];
    const float* Wfc = (const float*)d_in[9]; const float* bfc = (const float*)d_in[10];
    float* out = (float*)d_out;

    char* wsb = (char*)d_ws;
    float* xn     = (float*)(wsb);                      // 256 KiB
    float* sq     = (float*)(wsb + (256u<<10));         // 256 KiB
    float* pooled = (float*)(wsb + (512u<<10));         // 512 KiB
    bf16* Wt2     = (bf16*)(wsb + (1280u<<10));         // 36 KiB
    bf16* Wt3     = (bf16*)(wsb + (1316u<<10));         // 144 KiB
    bf16* Wt4     = (bf16*)(wsb + (1460u<<10));         // 576 KiB
    bf16* W1b     = (bf16*)(wsb + (2036u<<10));         // 2 KiB
    bf16* zbuf    = (bf16*)(wsb + (2040u<<10));         // 1 KiB (zeroed below)
    char* chunk_base = wsb + (2048u<<10);               // 2 MiB header

    // Per-image: only h2 (NHWC bf16, 128 KiB) is materialized now
    const size_t perImg = 32u*32u*64u*2u;
    int chunk = 4;
    for (int c = 512; c >= 4; c >>= 1) {
        if ((2048u<<10) + (size_t)c * perImg <= ws_size) { chunk = c; break; }
    }

    hipMemsetAsync(zbuf, 0, 1024, stream);
    gaf_stats_kernel<<<kBC, kS, 0, stream>>>(x_raw, xn, sq);
    wtrans_all_kernel<<<(388096 + 255)/256, 256, 0, stream>>>(W1, W2, W3, W4, W1b, Wt2, Wt3, Wt4);

    for (int img0 = 0; img0 < kBC; img0 += chunk) {
        int nimg = chunk;
        bf16* h2 = (bf16*)chunk_base;

        // fused conv1+conv2: 2->32->64, 128->64->32
        conv12_kernel<<<dim3(8, nimg), 256, 0, stream>>>(xn, sq, W1b, b1, Wt2, b2, h2, img0);
        // fused conv3+conv4 (+pool): 64->128->256, 32->16->8->pool
        conv34_kernel<<<nimg, 256, 0, stream>>>(h2, Wt3, b3, Wt4, b4, pooled, img0, zbuf);
    }

    poolfc_kernel<<<kB, kLatent, 0, stream>>>(pooled, Wfc, bfc, out);
}